// Round 2
// baseline (4484.963 us; speedup 1.0000x reference)
//
#include <hip/hip_runtime.h>

typedef unsigned short bf16_t;

__device__ __forceinline__ float b2f(bf16_t u) {
    return __uint_as_float(((unsigned int)u) << 16);
}
__device__ __forceinline__ bf16_t f2b(float f) {
    unsigned int x = __float_as_uint(f);
    unsigned int r = x + 0x7fffu + ((x >> 16) & 1u);
    return (bf16_t)(r >> 16);
}
__device__ __forceinline__ float ldf(const void* p, int i, int isf) {
    return isf ? ((const float*)p)[i] : b2f(((const bf16_t*)p)[i]);
}

// ---- params block offsets (floats) ----
#define OFF_S0T0 0
#define OFF_W1   16
#define OFF_S1   592
#define OFF_H1   656
#define OFF_S2   720
#define OFF_H2   784
#define OFF_S3   848
#define OFF_H3   912
#define OFF_S4   976
#define OFF_H4   1040
#define OFF_SC5  1104
#define OFF_H5   1112
#define OFF_SC6  1624
#define OFF_H6   1632
#define OFF_SC7  2144
#define OFF_H7   2152
#define OFF_W8   2280
#define OFF_B8   3304
#define OFF_FLAG 4032

// ---------------------------------------------------------------------------
// dtype detector: bf16 storage => asfloat(word<<16) is a sane N(0,1) magnitude
// for ~all words; fp32 storage => exponent bits are random mantissa bits.
// ---------------------------------------------------------------------------
__global__ void detect_kernel(const void* xraw, float* prm)
{
    if (threadIdx.x == 0 && blockIdx.x == 0) {
        const unsigned int* w = (const unsigned int*)xraw;
        int good = 0;
        for (int i = 0; i < 64; i++) {
            float f = __uint_as_float(w[i] << 16);
            float a = fabsf(f);
            if (a >= 0.0009765625f && a <= 16.0f) good++;
        }
        prm[OFF_FLAG] = (good >= 32) ? 0.0f : 1.0f;  // many good => bf16
    }
}

// generic element convert to fp32
__global__ __launch_bounds__(256) void cvt_kernel(
    const void* __restrict__ src, float* __restrict__ dst, int n,
    const float* __restrict__ prm)
{
    const int isf = prm[OFF_FLAG] > 0.5f;
    int i = blockIdx.x * 256 + threadIdx.x;
    if (i < n) dst[i] = ldf(src, i, isf);
}

// fold all small tensors + BN params into the fp32 params block
__global__ __launch_bounds__(256) void fold_params_kernel(
    const void* bn0p, const void* w1, const void* b1, const void* bn1p,
    const void* b2c, const void* bn2p, const void* bn3p, const void* bn4p,
    const void* b5, const void* bn5p, const void* b6, const void* bn6p,
    const void* b7, const void* bn7p, const void* w8, const void* b8,
    float* prm)
{
    const int isf = prm[OFF_FLAG] > 0.5f;
    const int t = threadIdx.x;

    if (t == 0) {
        float g = ldf(bn0p, 0, isf), be = ldf(bn0p, 1, isf);
        float m = ldf(bn0p, 2, isf), v = ldf(bn0p, 3, isf);
        float s = g * rsqrtf(v + 1e-5f);
        prm[OFF_S0T0] = s; prm[OFF_S0T0 + 1] = be - m * s;
    }
    for (int i = t; i < 576; i += 256) prm[OFF_W1 + i] = ldf(w1, i, isf);

    if (t < 64) {
        {   // bn1 (+conv1 bias)
            float g = ldf(bn1p, t, isf), be = ldf(bn1p, 64 + t, isf);
            float m = ldf(bn1p, 128 + t, isf), v = ldf(bn1p, 192 + t, isf);
            float s = g * rsqrtf(v + 1e-5f);
            prm[OFF_S1 + t] = s;
            prm[OFF_H1 + t] = s * ldf(b1, t, isf) + (be - m * s);
        }
        {   // bn2 (+conv2 bias)
            float g = ldf(bn2p, t, isf), be = ldf(bn2p, 64 + t, isf);
            float m = ldf(bn2p, 128 + t, isf), v = ldf(bn2p, 192 + t, isf);
            float s = g * rsqrtf(v + 1e-5f);
            prm[OFF_S2 + t] = s;
            prm[OFF_H2 + t] = s * ldf(b2c, t, isf) + (be - m * s);
        }
        {   // bn3 (no bias)
            float g = ldf(bn3p, t, isf), be = ldf(bn3p, 64 + t, isf);
            float m = ldf(bn3p, 128 + t, isf), v = ldf(bn3p, 192 + t, isf);
            float s = g * rsqrtf(v + 1e-5f);
            prm[OFF_S3 + t] = s;
            prm[OFF_H3 + t] = be - m * s;
        }
        {   // bn4 (no bias)
            float g = ldf(bn4p, t, isf), be = ldf(bn4p, 64 + t, isf);
            float m = ldf(bn4p, 128 + t, isf), v = ldf(bn4p, 192 + t, isf);
            float s = g * rsqrtf(v + 1e-5f);
            prm[OFF_S4 + t] = s;
            prm[OFF_H4 + t] = be - m * s;
        }
    }
    {   // fc5 scalar bn + bias fold
        float g = ldf(bn5p, 0, isf), be = ldf(bn5p, 1, isf);
        float m = ldf(bn5p, 2, isf), v = ldf(bn5p, 3, isf);
        float s = g * rsqrtf(v + 1e-5f);
        if (t == 0) prm[OFF_SC5] = s;
        for (int i = t; i < 512; i += 256)
            prm[OFF_H5 + i] = s * ldf(b5, i, isf) + (be - m * s);
    }
    {   // fc6
        float g = ldf(bn6p, 0, isf), be = ldf(bn6p, 1, isf);
        float m = ldf(bn6p, 2, isf), v = ldf(bn6p, 3, isf);
        float s = g * rsqrtf(v + 1e-5f);
        if (t == 0) prm[OFF_SC6] = s;
        for (int i = t; i < 512; i += 256)
            prm[OFF_H6 + i] = s * ldf(b6, i, isf) + (be - m * s);
    }
    {   // fc7
        float g = ldf(bn7p, 0, isf), be = ldf(bn7p, 1, isf);
        float m = ldf(bn7p, 2, isf), v = ldf(bn7p, 3, isf);
        float s = g * rsqrtf(v + 1e-5f);
        if (t == 0) prm[OFF_SC7] = s;
        if (t < 128) prm[OFF_H7 + t] = s * ldf(b7, t, isf) + (be - m * s);
    }
    for (int i = t; i < 1024; i += 256) prm[OFF_W8 + i] = ldf(w8, i, isf);
    if (t < 8) prm[OFF_B8 + t] = ldf(b8, t, isf);
}

// ---------------------------------------------------------------------------
// Front: transpose+bn0 -> conv1+bn1+relu -> conv2+bn2+relu -> lc3+bn3+relu
//        -> lc4+bn4+relu -> outh[b][c*128+p].  One block per sample, pure fp32.
// ---------------------------------------------------------------------------
__global__ __launch_bounds__(256) void front_kernel(
    const float* __restrict__ xf, const float* __restrict__ prm,
    const float* __restrict__ w2f, const float* __restrict__ w3f,
    const float* __restrict__ w4f, float* __restrict__ outh)
{
    __shared__ float sm[16384];          // 64 KiB
    float* actA = sm;                    // [64][128]
    float* actB = sm + 8192;             // [64][128]
    float* xn   = sm + 8192;             // [10][18], aliases actB (dead then)
    float* w1s  = sm + 8192 + 192;       // 576 conv1 weights, aliases actB

    const int t = threadIdx.x;
    const int b = blockIdx.x;

    const float s0 = prm[OFF_S0T0], t0 = prm[OFF_S0T0 + 1];

    for (int i = t; i < 576; i += 256) w1s[i] = prm[OFF_W1 + i];
    if (t < 180) {
        int row = t / 18, col = t - row * 18;
        float v = 0.f;
        if (row >= 1 && row <= 8 && col >= 1 && col <= 16)
            v = s0 * xf[(size_t)b * 128 + (col - 1) * 8 + (row - 1)] + t0;
        xn[t] = v;
    }
    __syncthreads();

    const int pg  = t & 31;
    const int oc0 = (t >> 5) * 8;

    // ---- conv1 + bn1 + relu -> actA ----
    {
        float s1[8], h1[8];
        #pragma unroll
        for (int j = 0; j < 8; j++) {
            s1[j] = prm[OFF_S1 + oc0 + j];
            h1[j] = prm[OFF_H1 + oc0 + j];
        }
        #pragma unroll
        for (int m = 0; m < 4; m++) {
            int p = pg + 32 * m;
            int h = p >> 4, w = p & 15;
            float r[9];
            #pragma unroll
            for (int dh = 0; dh < 3; dh++)
                #pragma unroll
                for (int dw = 0; dw < 3; dw++)
                    r[dh * 3 + dw] = xn[(h + dh) * 18 + (w + dw)];
            #pragma unroll
            for (int j = 0; j < 8; j++) {
                float acc = 0.f;
                #pragma unroll
                for (int k = 0; k < 9; k++) acc += r[k] * w1s[(oc0 + j) * 9 + k];
                actA[(oc0 + j) * 128 + p] = fmaxf(s1[j] * acc + h1[j], 0.f);
            }
        }
    }
    __syncthreads();

    // ---- conv2 + bn2 + relu : actA -> actB ----
    {
        float acc[4][8];
        #pragma unroll
        for (int m = 0; m < 4; m++)
            #pragma unroll
            for (int j = 0; j < 8; j++) acc[m][j] = 0.f;

        #pragma unroll
        for (int tap = 0; tap < 9; tap++) {
            const int dh = tap / 3 - 1, dw = tap % 3 - 1;
            int adr[4]; float msk[4];
            #pragma unroll
            for (int m = 0; m < 4; m++) {
                int p = pg + 32 * m;
                int h = (p >> 4) + dh, w = (p & 15) + dw;
                bool v = (h >= 0) && (h < 8) && (w >= 0) && (w < 16);
                adr[m] = v ? (h * 16 + w) : 0;
                msk[m] = v ? 1.f : 0.f;
            }
            for (int ic = 0; ic < 64; ic++) {
                float a0 = msk[0] * actA[ic * 128 + adr[0]];
                float a1 = msk[1] * actA[ic * 128 + adr[1]];
                float a2 = msk[2] * actA[ic * 128 + adr[2]];
                float a3 = msk[3] * actA[ic * 128 + adr[3]];
                const float* wp = w2f + (size_t)(oc0 * 64 + ic) * 9 + tap;
                #pragma unroll
                for (int j = 0; j < 8; j++) {
                    float wj = wp[(size_t)j * 576];
                    acc[0][j] += a0 * wj;
                    acc[1][j] += a1 * wj;
                    acc[2][j] += a2 * wj;
                    acc[3][j] += a3 * wj;
                }
            }
        }
        #pragma unroll
        for (int j = 0; j < 8; j++) {
            int oc = oc0 + j;
            float s = prm[OFF_S2 + oc], h = prm[OFF_H2 + oc];
            #pragma unroll
            for (int m = 0; m < 4; m++)
                actB[oc * 128 + pg + 32 * m] = fmaxf(s * acc[m][j] + h, 0.f);
        }
    }
    __syncthreads();

    // ---- lc3 + bn3 + relu : actB -> actA ----
    {
        float acc[4][8];
        #pragma unroll
        for (int m = 0; m < 4; m++)
            #pragma unroll
            for (int j = 0; j < 8; j++) acc[m][j] = 0.f;

        for (int ic = 0; ic < 64; ic++) {
            float a0 = actB[ic * 128 + pg];
            float a1 = actB[ic * 128 + pg + 32];
            float a2 = actB[ic * 128 + pg + 64];
            float a3 = actB[ic * 128 + pg + 96];
            const float* wp = w3f + (size_t)(oc0 * 64 + ic) * 128 + pg;
            #pragma unroll
            for (int j = 0; j < 8; j++) {
                const float* wpj = wp + (size_t)j * 8192;
                acc[0][j] += a0 * wpj[0];
                acc[1][j] += a1 * wpj[32];
                acc[2][j] += a2 * wpj[64];
                acc[3][j] += a3 * wpj[96];
            }
        }
        #pragma unroll
        for (int j = 0; j < 8; j++) {
            int oc = oc0 + j;
            float s = prm[OFF_S3 + oc], h = prm[OFF_H3 + oc];
            #pragma unroll
            for (int m = 0; m < 4; m++)
                actA[oc * 128 + pg + 32 * m] = fmaxf(s * acc[m][j] + h, 0.f);
        }
    }
    __syncthreads();

    // ---- lc4 + bn4 + relu : actA -> global ----
    {
        float acc[4][8];
        #pragma unroll
        for (int m = 0; m < 4; m++)
            #pragma unroll
            for (int j = 0; j < 8; j++) acc[m][j] = 0.f;

        for (int ic = 0; ic < 64; ic++) {
            float a0 = actA[ic * 128 + pg];
            float a1 = actA[ic * 128 + pg + 32];
            float a2 = actA[ic * 128 + pg + 64];
            float a3 = actA[ic * 128 + pg + 96];
            const float* wp = w4f + (size_t)(oc0 * 64 + ic) * 128 + pg;
            #pragma unroll
            for (int j = 0; j < 8; j++) {
                const float* wpj = wp + (size_t)j * 8192;
                acc[0][j] += a0 * wpj[0];
                acc[1][j] += a1 * wpj[32];
                acc[2][j] += a2 * wpj[64];
                acc[3][j] += a3 * wpj[96];
            }
        }
        float* ob = outh + (size_t)b * 8192;
        #pragma unroll
        for (int j = 0; j < 8; j++) {
            int oc = oc0 + j;
            float s = prm[OFF_S4 + oc], h = prm[OFF_H4 + oc];
            #pragma unroll
            for (int m = 0; m < 4; m++)
                ob[oc * 128 + pg + 32 * m] = fmaxf(s * acc[m][j] + h, 0.f);
        }
    }
}

// ---------------------------------------------------------------------------
// GEMM: out[M][N] = relu(scale * (A[M][K] . W[N][K]) + shift[n])
// 64x64 tile, 256 threads, 4x4 per thread, K-step 16, all fp32.
// ---------------------------------------------------------------------------
__global__ __launch_bounds__(256) void gemm_bn_relu(
    const float* __restrict__ A, const float* __restrict__ W,
    const float* __restrict__ prm, int sc_off, int sh_off,
    float* __restrict__ out, int K, int N)
{
    __shared__ float As[64][17];
    __shared__ float Bs[64][17];
    const int t  = threadIdx.x;
    const int m0 = blockIdx.x * 64, n0 = blockIdx.y * 64;
    const int lr = t >> 2, lc = (t & 3) * 4;
    const int tr = t >> 4, tc = t & 15;

    float acc[4][4];
    #pragma unroll
    for (int i = 0; i < 4; i++)
        #pragma unroll
        for (int j = 0; j < 4; j++) acc[i][j] = 0.f;

    for (int k0 = 0; k0 < K; k0 += 16) {
        const float4 av = *(const float4*)(A + (size_t)(m0 + lr) * K + k0 + lc);
        As[lr][lc] = av.x; As[lr][lc + 1] = av.y; As[lr][lc + 2] = av.z; As[lr][lc + 3] = av.w;
        const float4 wv = *(const float4*)(W + (size_t)(n0 + lr) * K + k0 + lc);
        Bs[lr][lc] = wv.x; Bs[lr][lc + 1] = wv.y; Bs[lr][lc + 2] = wv.z; Bs[lr][lc + 3] = wv.w;
        __syncthreads();
        #pragma unroll
        for (int kk = 0; kk < 16; kk++) {
            float a[4], bb[4];
            #pragma unroll
            for (int i = 0; i < 4; i++) a[i] = As[tr * 4 + i][kk];
            #pragma unroll
            for (int j = 0; j < 4; j++) bb[j] = Bs[tc * 4 + j][kk];
            #pragma unroll
            for (int i = 0; i < 4; i++)
                #pragma unroll
                for (int j = 0; j < 4; j++) acc[i][j] += a[i] * bb[j];
        }
        __syncthreads();
    }

    const float s = prm[sc_off];
    float bi[4];
    #pragma unroll
    for (int j = 0; j < 4; j++) bi[j] = prm[sh_off + n0 + tc * 4 + j];
    #pragma unroll
    for (int i = 0; i < 4; i++) {
        int row = m0 + tr * 4 + i;
        float4 o;
        o.x = fmaxf(s * acc[i][0] + bi[0], 0.f);
        o.y = fmaxf(s * acc[i][1] + bi[1], 0.f);
        o.z = fmaxf(s * acc[i][2] + bi[2], 0.f);
        o.w = fmaxf(s * acc[i][3] + bi[3], 0.f);
        *(float4*)(out + (size_t)row * N + n0 + tc * 4) = o;
    }
}

// ---------------------------------------------------------------------------
// fc8: out[b][n] = h[b][:] . w8[n][:] + b8[n]   (N=8, K=128)
// output dtype chosen at runtime from detected flag.
// ---------------------------------------------------------------------------
__global__ __launch_bounds__(256) void fc8_kernel(
    const float* __restrict__ h, const float* __restrict__ prm,
    void* __restrict__ out, int c0)
{
    __shared__ float wsm[8 * 129];
    const int t = threadIdx.x;
    for (int i = t; i < 1024; i += 256) {
        int n = i >> 7, k = i & 127;
        wsm[n * 129 + k] = prm[OFF_W8 + i];
    }
    __syncthreads();
    const int isf = prm[OFF_FLAG] > 0.5f;
    const int bl = t >> 3, n = t & 7;
    const int b = c0 + blockIdx.x * 32 + bl;
    const float* hb = h + (size_t)(blockIdx.x * 32 + bl) * 128;
    float acc = prm[OFF_B8 + n];
    for (int k = 0; k < 128; k++) acc += hb[k] * wsm[n * 129 + k];
    if (isf) ((float*)out)[(size_t)b * 8 + n] = acc;
    else     ((bf16_t*)out)[(size_t)b * 8 + n] = f2b(acc);
}

// ---------------------------------------------------------------------------
extern "C" void kernel_launch(void* const* d_in, const int* in_sizes, int n_in,
                              void* d_out, int out_size, void* d_ws, size_t ws_size,
                              hipStream_t stream)
{
    const void* x    = d_in[0];
    const void* bn0p = d_in[1];
    const void* w1   = d_in[2];
    const void* b1   = d_in[3];
    const void* bn1p = d_in[4];
    const void* w2   = d_in[5];
    const void* b2c  = d_in[6];
    const void* bn2p = d_in[7];
    const void* w3   = d_in[8];
    const void* bn3p = d_in[9];
    const void* w4   = d_in[10];
    const void* bn4p = d_in[11];
    const void* w5   = d_in[12];
    const void* b5   = d_in[13];
    const void* bn5p = d_in[14];
    const void* w6   = d_in[15];
    const void* b6   = d_in[16];
    const void* bn6p = d_in[17];
    const void* w7   = d_in[18];
    const void* b7   = d_in[19];
    const void* bn7p = d_in[20];
    const void* w8   = d_in[21];
    const void* b8   = d_in[22];

    float* base = (float*)d_ws;
    float* prm  = base;                    // 4096
    float* w2f  = base + 4096;             // 36864
    float* w3f  = base + 40960;            // 524288
    float* w4f  = base + 565248;           // 524288
    float* w5f  = base + 1089536;          // 4194304
    float* w6f  = base + 5283840;          // 262144
    float* w7f  = base + 5545984;          // 65536
    float* xf   = base + 5611520;          // 1048576
    float* acts = base + 6660096;

    const int B = 8192;
    const size_t FIXED = 6660096ull * 4ull;
    size_t avail = (ws_size > FIXED) ? (ws_size - FIXED) : 0;
    int Bc = 8192;
    while (Bc > 64 && (size_t)Bc * 37376ull > avail) Bc >>= 1;

    float* bufA = acts;                              // [Bc][8192]
    float* bufC = bufA + (size_t)Bc * 8192;          // [Bc][512]
    float* bufD = bufC + (size_t)Bc * 512;           // [Bc][512]
    float* bufE = bufD + (size_t)Bc * 512;           // [Bc][128]

    detect_kernel<<<1, 64, 0, stream>>>(x, prm);
    fold_params_kernel<<<1, 256, 0, stream>>>(
        bn0p, w1, b1, bn1p, b2c, bn2p, bn3p, bn4p,
        b5, bn5p, b6, bn6p, b7, bn7p, w8, b8, prm);

    cvt_kernel<<<(36864 + 255) / 256, 256, 0, stream>>>(w2, w2f, 36864, prm);
    cvt_kernel<<<(524288 + 255) / 256, 256, 0, stream>>>(w3, w3f, 524288, prm);
    cvt_kernel<<<(524288 + 255) / 256, 256, 0, stream>>>(w4, w4f, 524288, prm);
    cvt_kernel<<<(4194304 + 255) / 256, 256, 0, stream>>>(w5, w5f, 4194304, prm);
    cvt_kernel<<<(262144 + 255) / 256, 256, 0, stream>>>(w6, w6f, 262144, prm);
    cvt_kernel<<<(65536 + 255) / 256, 256, 0, stream>>>(w7, w7f, 65536, prm);
    cvt_kernel<<<(1048576 + 255) / 256, 256, 0, stream>>>(x, xf, 1048576, prm);

    for (int c0 = 0; c0 < B; c0 += Bc) {
        front_kernel<<<Bc, 256, 0, stream>>>(
            xf + (size_t)c0 * 128, prm, w2f, w3f, w4f, bufA);
        gemm_bn_relu<<<dim3(Bc / 64, 8), 256, 0, stream>>>(
            bufA, w5f, prm, OFF_SC5, OFF_H5, bufC, 8192, 512);
        gemm_bn_relu<<<dim3(Bc / 64, 8), 256, 0, stream>>>(
            bufC, w6f, prm, OFF_SC6, OFF_H6, bufD, 512, 512);
        gemm_bn_relu<<<dim3(Bc / 64, 2), 256, 0, stream>>>(
            bufD, w7f, prm, OFF_SC7, OFF_H7, bufE, 512, 128);
        fc8_kernel<<<Bc / 32, 256, 0, stream>>>(bufE, prm, d_out, c0);
    }
}

// Round 3
// 2993.908 us; speedup vs baseline: 1.4980x; 1.4980x over previous
//
#include <hip/hip_runtime.h>

typedef unsigned short bf16_t;
typedef __attribute__((ext_vector_type(8))) short bf16x8;
typedef __attribute__((ext_vector_type(4))) float f32x4;

__device__ __forceinline__ float b2f(bf16_t u) {
    return __uint_as_float(((unsigned int)u) << 16);
}
__device__ __forceinline__ bf16_t f2b(float f) {
    unsigned int x = __float_as_uint(f);
    unsigned int r = x + 0x7fffu + ((x >> 16) & 1u);
    return (bf16_t)(r >> 16);
}
__device__ __forceinline__ float ldf(const void* p, int i, int isf) {
    return isf ? ((const float*)p)[i] : b2f(((const bf16_t*)p)[i]);
}

// ---- params block offsets (floats) ----
#define OFF_S0T0 0
#define OFF_W1   16
#define OFF_S1   592
#define OFF_H1   656
#define OFF_S2   720
#define OFF_H2   784
#define OFF_S3   848
#define OFF_H3   912
#define OFF_S4   976
#define OFF_H4   1040
#define OFF_SC5  1104
#define OFF_H5   1112
#define OFF_SC6  1624
#define OFF_H6   1632
#define OFF_SC7  2144
#define OFF_H7   2152
#define OFF_W8   2280
#define OFF_B8   3304
#define OFF_FLAG 4032

// ---------------------------------------------------------------------------
// dtype detector: bf16 storage => asfloat(word<<16) is a sane N(0,1) magnitude
// for ~all words; fp32 storage => exponent bits are random mantissa bits.
// ---------------------------------------------------------------------------
__global__ void detect_kernel(const void* xraw, float* prm)
{
    if (threadIdx.x == 0 && blockIdx.x == 0) {
        const unsigned int* w = (const unsigned int*)xraw;
        int good = 0;
        for (int i = 0; i < 64; i++) {
            float f = __uint_as_float(w[i] << 16);
            float a = fabsf(f);
            if (a >= 0.0009765625f && a <= 16.0f) good++;
        }
        prm[OFF_FLAG] = (good >= 32) ? 0.0f : 1.0f;  // many good => bf16
    }
}

// element convert to fp32
__global__ __launch_bounds__(256) void cvt_kernel(
    const void* __restrict__ src, float* __restrict__ dst, int n,
    const float* __restrict__ prm)
{
    const int isf = prm[OFF_FLAG] > 0.5f;
    int i = blockIdx.x * 256 + threadIdx.x;
    if (i < n) dst[i] = ldf(src, i, isf);
}

// element convert to bf16 (from either storage dtype)
__global__ __launch_bounds__(256) void cvtb_kernel(
    const void* __restrict__ src, bf16_t* __restrict__ dst, int n,
    const float* __restrict__ prm)
{
    const int isf = prm[OFF_FLAG] > 0.5f;
    int i = blockIdx.x * 256 + threadIdx.x;
    if (i < n) dst[i] = isf ? f2b(((const float*)src)[i]) : ((const bf16_t*)src)[i];
}

// fold all small tensors + BN params into the fp32 params block
__global__ __launch_bounds__(256) void fold_params_kernel(
    const void* bn0p, const void* w1, const void* b1, const void* bn1p,
    const void* b2c, const void* bn2p, const void* bn3p, const void* bn4p,
    const void* b5, const void* bn5p, const void* b6, const void* bn6p,
    const void* b7, const void* bn7p, const void* w8, const void* b8,
    float* prm)
{
    const int isf = prm[OFF_FLAG] > 0.5f;
    const int t = threadIdx.x;

    if (t == 0) {
        float g = ldf(bn0p, 0, isf), be = ldf(bn0p, 1, isf);
        float m = ldf(bn0p, 2, isf), v = ldf(bn0p, 3, isf);
        float s = g * rsqrtf(v + 1e-5f);
        prm[OFF_S0T0] = s; prm[OFF_S0T0 + 1] = be - m * s;
    }
    for (int i = t; i < 576; i += 256) prm[OFF_W1 + i] = ldf(w1, i, isf);

    if (t < 64) {
        {
            float g = ldf(bn1p, t, isf), be = ldf(bn1p, 64 + t, isf);
            float m = ldf(bn1p, 128 + t, isf), v = ldf(bn1p, 192 + t, isf);
            float s = g * rsqrtf(v + 1e-5f);
            prm[OFF_S1 + t] = s;
            prm[OFF_H1 + t] = s * ldf(b1, t, isf) + (be - m * s);
        }
        {
            float g = ldf(bn2p, t, isf), be = ldf(bn2p, 64 + t, isf);
            float m = ldf(bn2p, 128 + t, isf), v = ldf(bn2p, 192 + t, isf);
            float s = g * rsqrtf(v + 1e-5f);
            prm[OFF_S2 + t] = s;
            prm[OFF_H2 + t] = s * ldf(b2c, t, isf) + (be - m * s);
        }
        {
            float g = ldf(bn3p, t, isf), be = ldf(bn3p, 64 + t, isf);
            float m = ldf(bn3p, 128 + t, isf), v = ldf(bn3p, 192 + t, isf);
            float s = g * rsqrtf(v + 1e-5f);
            prm[OFF_S3 + t] = s;
            prm[OFF_H3 + t] = be - m * s;
        }
        {
            float g = ldf(bn4p, t, isf), be = ldf(bn4p, 64 + t, isf);
            float m = ldf(bn4p, 128 + t, isf), v = ldf(bn4p, 192 + t, isf);
            float s = g * rsqrtf(v + 1e-5f);
            prm[OFF_S4 + t] = s;
            prm[OFF_H4 + t] = be - m * s;
        }
    }
    {
        float g = ldf(bn5p, 0, isf), be = ldf(bn5p, 1, isf);
        float m = ldf(bn5p, 2, isf), v = ldf(bn5p, 3, isf);
        float s = g * rsqrtf(v + 1e-5f);
        if (t == 0) prm[OFF_SC5] = s;
        for (int i = t; i < 512; i += 256)
            prm[OFF_H5 + i] = s * ldf(b5, i, isf) + (be - m * s);
    }
    {
        float g = ldf(bn6p, 0, isf), be = ldf(bn6p, 1, isf);
        float m = ldf(bn6p, 2, isf), v = ldf(bn6p, 3, isf);
        float s = g * rsqrtf(v + 1e-5f);
        if (t == 0) prm[OFF_SC6] = s;
        for (int i = t; i < 512; i += 256)
            prm[OFF_H6 + i] = s * ldf(b6, i, isf) + (be - m * s);
    }
    {
        float g = ldf(bn7p, 0, isf), be = ldf(bn7p, 1, isf);
        float m = ldf(bn7p, 2, isf), v = ldf(bn7p, 3, isf);
        float s = g * rsqrtf(v + 1e-5f);
        if (t == 0) prm[OFF_SC7] = s;
        if (t < 128) prm[OFF_H7 + t] = s * ldf(b7, t, isf) + (be - m * s);
    }
    for (int i = t; i < 1024; i += 256) prm[OFF_W8 + i] = ldf(w8, i, isf);
    if (t < 8) prm[OFF_B8 + t] = ldf(b8, t, isf);
}

// ---------------------------------------------------------------------------
// Front: transpose+bn0 -> conv1+bn1+relu -> conv2+bn2+relu -> lc3+bn3+relu
//        -> lc4+bn4+relu -> bf16 outh[b][c*128+p].  One block per sample.
// ---------------------------------------------------------------------------
__global__ __launch_bounds__(256) void front_kernel(
    const float* __restrict__ xf, const float* __restrict__ prm,
    const float* __restrict__ w2f, const float* __restrict__ w3f,
    const float* __restrict__ w4f, bf16_t* __restrict__ outh)
{
    __shared__ float sm[16384];          // 64 KiB
    float* actA = sm;                    // [64][128]
    float* actB = sm + 8192;             // [64][128]
    float* xn   = sm + 8192;             // [10][18], aliases actB (dead then)
    float* w1s  = sm + 8192 + 192;       // 576 conv1 weights, aliases actB

    const int t = threadIdx.x;
    const int b = blockIdx.x;

    const float s0 = prm[OFF_S0T0], t0 = prm[OFF_S0T0 + 1];

    for (int i = t; i < 576; i += 256) w1s[i] = prm[OFF_W1 + i];
    if (t < 180) {
        int row = t / 18, col = t - row * 18;
        float v = 0.f;
        if (row >= 1 && row <= 8 && col >= 1 && col <= 16)
            v = s0 * xf[(size_t)b * 128 + (col - 1) * 8 + (row - 1)] + t0;
        xn[t] = v;
    }
    __syncthreads();

    const int pg  = t & 31;
    const int oc0 = (t >> 5) * 8;

    // ---- conv1 + bn1 + relu -> actA ----
    {
        float s1[8], h1[8];
        #pragma unroll
        for (int j = 0; j < 8; j++) {
            s1[j] = prm[OFF_S1 + oc0 + j];
            h1[j] = prm[OFF_H1 + oc0 + j];
        }
        #pragma unroll
        for (int m = 0; m < 4; m++) {
            int p = pg + 32 * m;
            int h = p >> 4, w = p & 15;
            float r[9];
            #pragma unroll
            for (int dh = 0; dh < 3; dh++)
                #pragma unroll
                for (int dw = 0; dw < 3; dw++)
                    r[dh * 3 + dw] = xn[(h + dh) * 18 + (w + dw)];
            #pragma unroll
            for (int j = 0; j < 8; j++) {
                float acc = 0.f;
                #pragma unroll
                for (int k = 0; k < 9; k++) acc += r[k] * w1s[(oc0 + j) * 9 + k];
                actA[(oc0 + j) * 128 + p] = fmaxf(s1[j] * acc + h1[j], 0.f);
            }
        }
    }
    __syncthreads();

    // ---- conv2 + bn2 + relu : actA -> actB ----
    {
        float acc[4][8];
        #pragma unroll
        for (int m = 0; m < 4; m++)
            #pragma unroll
            for (int j = 0; j < 8; j++) acc[m][j] = 0.f;

        #pragma unroll
        for (int tap = 0; tap < 9; tap++) {
            const int dh = tap / 3 - 1, dw = tap % 3 - 1;
            int adr[4]; float msk[4];
            #pragma unroll
            for (int m = 0; m < 4; m++) {
                int p = pg + 32 * m;
                int h = (p >> 4) + dh, w = (p & 15) + dw;
                bool v = (h >= 0) && (h < 8) && (w >= 0) && (w < 16);
                adr[m] = v ? (h * 16 + w) : 0;
                msk[m] = v ? 1.f : 0.f;
            }
            for (int ic = 0; ic < 64; ic++) {
                float a0 = msk[0] * actA[ic * 128 + adr[0]];
                float a1 = msk[1] * actA[ic * 128 + adr[1]];
                float a2 = msk[2] * actA[ic * 128 + adr[2]];
                float a3 = msk[3] * actA[ic * 128 + adr[3]];
                const float* wp = w2f + (size_t)(oc0 * 64 + ic) * 9 + tap;
                #pragma unroll
                for (int j = 0; j < 8; j++) {
                    float wj = wp[(size_t)j * 576];
                    acc[0][j] += a0 * wj;
                    acc[1][j] += a1 * wj;
                    acc[2][j] += a2 * wj;
                    acc[3][j] += a3 * wj;
                }
            }
        }
        #pragma unroll
        for (int j = 0; j < 8; j++) {
            int oc = oc0 + j;
            float s = prm[OFF_S2 + oc], h = prm[OFF_H2 + oc];
            #pragma unroll
            for (int m = 0; m < 4; m++)
                actB[oc * 128 + pg + 32 * m] = fmaxf(s * acc[m][j] + h, 0.f);
        }
    }
    __syncthreads();

    // ---- lc3 + bn3 + relu : actB -> actA ----
    {
        float acc[4][8];
        #pragma unroll
        for (int m = 0; m < 4; m++)
            #pragma unroll
            for (int j = 0; j < 8; j++) acc[m][j] = 0.f;

        for (int ic = 0; ic < 64; ic++) {
            float a0 = actB[ic * 128 + pg];
            float a1 = actB[ic * 128 + pg + 32];
            float a2 = actB[ic * 128 + pg + 64];
            float a3 = actB[ic * 128 + pg + 96];
            const float* wp = w3f + (size_t)(oc0 * 64 + ic) * 128 + pg;
            #pragma unroll
            for (int j = 0; j < 8; j++) {
                const float* wpj = wp + (size_t)j * 8192;
                acc[0][j] += a0 * wpj[0];
                acc[1][j] += a1 * wpj[32];
                acc[2][j] += a2 * wpj[64];
                acc[3][j] += a3 * wpj[96];
            }
        }
        #pragma unroll
        for (int j = 0; j < 8; j++) {
            int oc = oc0 + j;
            float s = prm[OFF_S3 + oc], h = prm[OFF_H3 + oc];
            #pragma unroll
            for (int m = 0; m < 4; m++)
                actA[oc * 128 + pg + 32 * m] = fmaxf(s * acc[m][j] + h, 0.f);
        }
    }
    __syncthreads();

    // ---- lc4 + bn4 + relu : actA -> global (bf16) ----
    {
        float acc[4][8];
        #pragma unroll
        for (int m = 0; m < 4; m++)
            #pragma unroll
            for (int j = 0; j < 8; j++) acc[m][j] = 0.f;

        for (int ic = 0; ic < 64; ic++) {
            float a0 = actA[ic * 128 + pg];
            float a1 = actA[ic * 128 + pg + 32];
            float a2 = actA[ic * 128 + pg + 64];
            float a3 = actA[ic * 128 + pg + 96];
            const float* wp = w4f + (size_t)(oc0 * 64 + ic) * 128 + pg;
            #pragma unroll
            for (int j = 0; j < 8; j++) {
                const float* wpj = wp + (size_t)j * 8192;
                acc[0][j] += a0 * wpj[0];
                acc[1][j] += a1 * wpj[32];
                acc[2][j] += a2 * wpj[64];
                acc[3][j] += a3 * wpj[96];
            }
        }
        bf16_t* ob = outh + (size_t)b * 8192;
        #pragma unroll
        for (int j = 0; j < 8; j++) {
            int oc = oc0 + j;
            float s = prm[OFF_S4 + oc], h = prm[OFF_H4 + oc];
            #pragma unroll
            for (int m = 0; m < 4; m++)
                ob[oc * 128 + pg + 32 * m] = f2b(fmaxf(s * acc[m][j] + h, 0.f));
        }
    }
}

// ---------------------------------------------------------------------------
// MFMA GEMM: out[M][N] = relu(scale * (A[M][K] . W[N][K]^T) + shift[n]), bf16.
// BM=BN=128, BK=32. 256 threads = 4 waves in 2x2, each wave 64x64 via
// 4x4 grid of 16x16x32 MFMA tiles. LDS row stride 40 shorts (conflict-free
// b128 frag reads, 16B-aligned rows).
// ---------------------------------------------------------------------------
__global__ __launch_bounds__(256) void gemm_mfma(
    const bf16_t* __restrict__ A, const bf16_t* __restrict__ W,
    const float* __restrict__ prm, int sc_off, int sh_off,
    bf16_t* __restrict__ out, int K, int N)
{
    __shared__ bf16_t As[128 * 40];
    __shared__ bf16_t Bs[128 * 40];
    const int t    = threadIdx.x;
    const int lane = t & 63;
    const int w    = t >> 6;
    const int wr   = w >> 1, wc = w & 1;
    const int m0   = blockIdx.x * 128, n0 = blockIdx.y * 128;

    // staging: A/B tiles are 128 rows x 32 k = 512 16B-chunks each;
    // thread covers chunks t and t+256 of each.
    const int r0 = t >> 2, q0 = (t & 3) * 8;     // rows 0..63
    const int r1 = r0 + 64;                      // rows 64..127

    f32x4 acc[4][4];
    #pragma unroll
    for (int i = 0; i < 4; i++)
        #pragma unroll
        for (int j = 0; j < 4; j++)
            acc[i][j] = (f32x4){0.f, 0.f, 0.f, 0.f};

    const int fr = lane & 15;
    const int fq = (lane >> 4) * 8;

    for (int k0 = 0; k0 < K; k0 += 32) {
        const uint4 a0v = *(const uint4*)(A + (size_t)(m0 + r0) * K + k0 + q0);
        const uint4 a1v = *(const uint4*)(A + (size_t)(m0 + r1) * K + k0 + q0);
        const uint4 b0v = *(const uint4*)(W + (size_t)(n0 + r0) * K + k0 + q0);
        const uint4 b1v = *(const uint4*)(W + (size_t)(n0 + r1) * K + k0 + q0);
        *(uint4*)(As + r0 * 40 + q0) = a0v;
        *(uint4*)(As + r1 * 40 + q0) = a1v;
        *(uint4*)(Bs + r0 * 40 + q0) = b0v;
        *(uint4*)(Bs + r1 * 40 + q0) = b1v;
        __syncthreads();

        bf16x8 af[4], bfr[4];
        #pragma unroll
        for (int i = 0; i < 4; i++) {
            af[i]  = *(const bf16x8*)(As + (wr * 64 + i * 16 + fr) * 40 + fq);
            bfr[i] = *(const bf16x8*)(Bs + (wc * 64 + i * 16 + fr) * 40 + fq);
        }
        #pragma unroll
        for (int i = 0; i < 4; i++)
            #pragma unroll
            for (int j = 0; j < 4; j++)
                acc[i][j] = __builtin_amdgcn_mfma_f32_16x16x32_bf16(
                    af[i], bfr[j], acc[i][j], 0, 0, 0);
        __syncthreads();
    }

    // epilogue: D row=(lane>>4)*4+reg, col=lane&15 within each 16x16 tile
    const float s    = prm[sc_off];
    const int   orow = (lane >> 4) * 4;
    const int   ocol = lane & 15;
    #pragma unroll
    for (int j = 0; j < 4; j++) {
        const int n  = n0 + wc * 64 + j * 16 + ocol;
        const float sh = prm[sh_off + n];
        #pragma unroll
        for (int i = 0; i < 4; i++) {
            const int mb = m0 + wr * 64 + i * 16 + orow;
            #pragma unroll
            for (int r = 0; r < 4; r++) {
                float v = fmaxf(s * acc[i][j][r] + sh, 0.f);
                out[(size_t)(mb + r) * N + n] = f2b(v);
            }
        }
    }
}

// ---------------------------------------------------------------------------
// fc8: out[b][n] = h[b][:] . w8[n][:] + b8[n]   (N=8, K=128), h is bf16
// ---------------------------------------------------------------------------
__global__ __launch_bounds__(256) void fc8_kernel(
    const bf16_t* __restrict__ h, const float* __restrict__ prm,
    void* __restrict__ out, int c0)
{
    __shared__ float wsm[8 * 129];
    const int t = threadIdx.x;
    for (int i = t; i < 1024; i += 256) {
        int n = i >> 7, k = i & 127;
        wsm[n * 129 + k] = prm[OFF_W8 + i];
    }
    __syncthreads();
    const int isf = prm[OFF_FLAG] > 0.5f;
    const int bl = t >> 3, n = t & 7;
    const int b = c0 + blockIdx.x * 32 + bl;
    const bf16_t* hb = h + (size_t)(blockIdx.x * 32 + bl) * 128;
    float acc = prm[OFF_B8 + n];
    for (int k = 0; k < 128; k++) acc += b2f(hb[k]) * wsm[n * 129 + k];
    if (isf) ((float*)out)[(size_t)b * 8 + n] = acc;
    else     ((bf16_t*)out)[(size_t)b * 8 + n] = f2b(acc);
}

// ---------------------------------------------------------------------------
extern "C" void kernel_launch(void* const* d_in, const int* in_sizes, int n_in,
                              void* d_out, int out_size, void* d_ws, size_t ws_size,
                              hipStream_t stream)
{
    const void* x    = d_in[0];
    const void* bn0p = d_in[1];
    const void* w1   = d_in[2];
    const void* b1   = d_in[3];
    const void* bn1p = d_in[4];
    const void* w2   = d_in[5];
    const void* b2c  = d_in[6];
    const void* bn2p = d_in[7];
    const void* w3   = d_in[8];
    const void* bn3p = d_in[9];
    const void* w4   = d_in[10];
    const void* bn4p = d_in[11];
    const void* w5   = d_in[12];
    const void* b5   = d_in[13];
    const void* bn5p = d_in[14];
    const void* w6   = d_in[15];
    const void* b6   = d_in[16];
    const void* bn6p = d_in[17];
    const void* w7   = d_in[18];
    const void* b7   = d_in[19];
    const void* bn7p = d_in[20];
    const void* w8   = d_in[21];
    const void* b8   = d_in[22];

    char* base = (char*)d_ws;
    float*  prm = (float*)(base + 0);            // 16384 B
    float*  w2f = (float*)(base + 16384);        // 147456 B
    float*  w3f = (float*)(base + 163840);       // 2097152 B
    float*  w4f = (float*)(base + 2260992);      // 2097152 B
    float*  xf  = (float*)(base + 4358144);      // 4194304 B
    bf16_t* w5b = (bf16_t*)(base + 8552448);     // 8388608 B
    bf16_t* w6b = (bf16_t*)(base + 16941056);    // 524288 B
    bf16_t* w7b = (bf16_t*)(base + 17465344);    // 131072 B
    char*   acts = base + 17596416;

    const int B = 8192;
    const size_t FIXED = 17596416ull;
    size_t avail = (ws_size > FIXED) ? (ws_size - FIXED) : 0;
    // per-sample: bufA 16384 + bufC 1024 + bufD 1024 + bufE 256 = 18688 B
    int Bc = 8192;
    while (Bc > 128 && (size_t)Bc * 18688ull > avail) Bc >>= 1;

    bf16_t* bufA = (bf16_t*)acts;                    // [Bc][8192]
    bf16_t* bufC = bufA + (size_t)Bc * 8192;         // [Bc][512]
    bf16_t* bufD = bufC + (size_t)Bc * 512;          // [Bc][512]
    bf16_t* bufE = bufD + (size_t)Bc * 512;          // [Bc][128]

    detect_kernel<<<1, 64, 0, stream>>>(x, prm);
    fold_params_kernel<<<1, 256, 0, stream>>>(
        bn0p, w1, b1, bn1p, b2c, bn2p, bn3p, bn4p,
        b5, bn5p, b6, bn6p, b7, bn7p, w8, b8, prm);

    cvt_kernel<<<(36864 + 255) / 256, 256, 0, stream>>>(w2, w2f, 36864, prm);
    cvt_kernel<<<(524288 + 255) / 256, 256, 0, stream>>>(w3, w3f, 524288, prm);
    cvt_kernel<<<(524288 + 255) / 256, 256, 0, stream>>>(w4, w4f, 524288, prm);
    cvt_kernel<<<(1048576 + 255) / 256, 256, 0, stream>>>(x, xf, 1048576, prm);
    cvtb_kernel<<<(4194304 + 255) / 256, 256, 0, stream>>>(w5, w5b, 4194304, prm);
    cvtb_kernel<<<(262144 + 255) / 256, 256, 0, stream>>>(w6, w6b, 262144, prm);
    cvtb_kernel<<<(65536 + 255) / 256, 256, 0, stream>>>(w7, w7b, 65536, prm);

    for (int c0 = 0; c0 < B; c0 += Bc) {
        front_kernel<<<Bc, 256, 0, stream>>>(
            xf + (size_t)c0 * 128, prm, w2f, w3f, w4f, bufA);
        gemm_mfma<<<dim3(Bc / 128, 4), 256, 0, stream>>>(
            bufA, w5b, prm, OFF_SC5, OFF_H5, bufC, 8192, 512);
        gemm_mfma<<<dim3(Bc / 128, 4), 256, 0, stream>>>(
            bufC, w6b, prm, OFF_SC6, OFF_H6, bufD, 512, 512);
        gemm_mfma<<<dim3(Bc / 128, 1), 256, 0, stream>>>(
            bufD, w7b, prm, OFF_SC7, OFF_H7, bufE, 512, 128);
        fc8_kernel<<<Bc / 32, 256, 0, stream>>>(bufE, prm, d_out, c0);
    }
}

// Round 4
// 807.546 us; speedup vs baseline: 5.5538x; 3.7074x over previous
//
#include <hip/hip_runtime.h>

typedef unsigned short bf16_t;
typedef __attribute__((ext_vector_type(8))) short bf16x8;
typedef __attribute__((ext_vector_type(8))) unsigned short u16x8;
typedef __attribute__((ext_vector_type(4))) float f32x4;

__device__ __forceinline__ float b2f(bf16_t u) {
    return __uint_as_float(((unsigned int)u) << 16);
}
__device__ __forceinline__ bf16_t f2b(float f) {
    unsigned int x = __float_as_uint(f);
    unsigned int r = x + 0x7fffu + ((x >> 16) & 1u);
    return (bf16_t)(r >> 16);
}
__device__ __forceinline__ float ldf(const void* p, int i, int isf) {
    return isf ? ((const float*)p)[i] : b2f(((const bf16_t*)p)[i]);
}

// ---- params block offsets (floats) ----
#define OFF_S0T0 0
#define OFF_W1   16
#define OFF_S1   592
#define OFF_H1   656
#define OFF_S2   720
#define OFF_H2   784
#define OFF_S3   848
#define OFF_H3   912
#define OFF_S4   976
#define OFF_H4   1040
#define OFF_SC5  1104
#define OFF_H5   1112
#define OFF_SC6  1624
#define OFF_H6   1632
#define OFF_SC7  2144
#define OFF_H7   2152
#define OFF_W8   2280
#define OFF_B8   3304
#define OFF_FLAG 4032

// ---------------------------------------------------------------------------
// dtype detector (bf16 vs fp32 storage), statistical on N(0,1) input x.
// ---------------------------------------------------------------------------
__global__ void detect_kernel(const void* xraw, float* prm)
{
    if (threadIdx.x == 0 && blockIdx.x == 0) {
        const unsigned int* w = (const unsigned int*)xraw;
        int good = 0;
        for (int i = 0; i < 64; i++) {
            float f = __uint_as_float(w[i] << 16);
            float a = fabsf(f);
            if (a >= 0.0009765625f && a <= 16.0f) good++;
        }
        prm[OFF_FLAG] = (good >= 32) ? 0.0f : 1.0f;  // many good => bf16
    }
}

// element convert to fp32
__global__ __launch_bounds__(256) void cvt_kernel(
    const void* __restrict__ src, float* __restrict__ dst, int n,
    const float* __restrict__ prm)
{
    const int isf = prm[OFF_FLAG] > 0.5f;
    int i = blockIdx.x * 256 + threadIdx.x;
    if (i < n) dst[i] = ldf(src, i, isf);
}

// element convert to bf16
__global__ __launch_bounds__(256) void cvtb_kernel(
    const void* __restrict__ src, bf16_t* __restrict__ dst, int n,
    const float* __restrict__ prm)
{
    const int isf = prm[OFF_FLAG] > 0.5f;
    int i = blockIdx.x * 256 + threadIdx.x;
    if (i < n) dst[i] = isf ? f2b(((const float*)src)[i]) : ((const bf16_t*)src)[i];
}

// w2 [oc][ic][tap] -> w2p [oc][tap*64+ic]   (n = 36864)
__global__ __launch_bounds__(256) void pw2_kernel(
    const void* __restrict__ src, bf16_t* __restrict__ dst,
    const float* __restrict__ prm)
{
    const int isf = prm[OFF_FLAG] > 0.5f;
    int i = blockIdx.x * 256 + threadIdx.x;
    if (i >= 36864) return;
    int oc = i / 576, r = i - oc * 576;
    int tap = r >> 6, ic = r & 63;
    dst[i] = f2b(ldf(src, oc * 576 + ic * 9 + tap, isf));
}

// w3/w4 [oc][ic][p] -> [p][oc*64+ic]   (n = 524288)
__global__ __launch_bounds__(256) void pw34_kernel(
    const void* __restrict__ src, bf16_t* __restrict__ dst,
    const float* __restrict__ prm)
{
    const int isf = prm[OFF_FLAG] > 0.5f;
    int i = blockIdx.x * 256 + threadIdx.x;
    if (i >= 524288) return;
    int p = i >> 12, r = i & 4095;
    int oc = r >> 6, ic = r & 63;
    dst[i] = f2b(ldf(src, oc * 8192 + ic * 128 + p, isf));
}

// w5 [n][c*128+p] -> w5p [n][p*64+c]   (n = 4194304)
__global__ __launch_bounds__(256) void pw5_kernel(
    const void* __restrict__ src, bf16_t* __restrict__ dst,
    const float* __restrict__ prm)
{
    const int isf = prm[OFF_FLAG] > 0.5f;
    int i = blockIdx.x * 256 + threadIdx.x;
    if (i >= 4194304) return;
    int nr = i >> 13, r = i & 8191;
    int p = r >> 6, c = r & 63;
    dst[i] = f2b(ldf(src, nr * 8192 + c * 128 + p, isf));
}

// fold all small tensors + BN params into the fp32 params block
__global__ __launch_bounds__(256) void fold_params_kernel(
    const void* bn0p, const void* w1, const void* b1, const void* bn1p,
    const void* b2c, const void* bn2p, const void* bn3p, const void* bn4p,
    const void* b5, const void* bn5p, const void* b6, const void* bn6p,
    const void* b7, const void* bn7p, const void* w8, const void* b8,
    float* prm)
{
    const int isf = prm[OFF_FLAG] > 0.5f;
    const int t = threadIdx.x;

    if (t == 0) {
        float g = ldf(bn0p, 0, isf), be = ldf(bn0p, 1, isf);
        float m = ldf(bn0p, 2, isf), v = ldf(bn0p, 3, isf);
        float s = g * rsqrtf(v + 1e-5f);
        prm[OFF_S0T0] = s; prm[OFF_S0T0 + 1] = be - m * s;
    }
    for (int i = t; i < 576; i += 256) prm[OFF_W1 + i] = ldf(w1, i, isf);

    if (t < 64) {
        {
            float g = ldf(bn1p, t, isf), be = ldf(bn1p, 64 + t, isf);
            float m = ldf(bn1p, 128 + t, isf), v = ldf(bn1p, 192 + t, isf);
            float s = g * rsqrtf(v + 1e-5f);
            prm[OFF_S1 + t] = s;
            prm[OFF_H1 + t] = s * ldf(b1, t, isf) + (be - m * s);
        }
        {
            float g = ldf(bn2p, t, isf), be = ldf(bn2p, 64 + t, isf);
            float m = ldf(bn2p, 128 + t, isf), v = ldf(bn2p, 192 + t, isf);
            float s = g * rsqrtf(v + 1e-5f);
            prm[OFF_S2 + t] = s;
            prm[OFF_H2 + t] = s * ldf(b2c, t, isf) + (be - m * s);
        }
        {
            float g = ldf(bn3p, t, isf), be = ldf(bn3p, 64 + t, isf);
            float m = ldf(bn3p, 128 + t, isf), v = ldf(bn3p, 192 + t, isf);
            float s = g * rsqrtf(v + 1e-5f);
            prm[OFF_S3 + t] = s;
            prm[OFF_H3 + t] = be - m * s;
        }
        {
            float g = ldf(bn4p, t, isf), be = ldf(bn4p, 64 + t, isf);
            float m = ldf(bn4p, 128 + t, isf), v = ldf(bn4p, 192 + t, isf);
            float s = g * rsqrtf(v + 1e-5f);
            prm[OFF_S4 + t] = s;
            prm[OFF_H4 + t] = be - m * s;
        }
    }
    {
        float g = ldf(bn5p, 0, isf), be = ldf(bn5p, 1, isf);
        float m = ldf(bn5p, 2, isf), v = ldf(bn5p, 3, isf);
        float s = g * rsqrtf(v + 1e-5f);
        if (t == 0) prm[OFF_SC5] = s;
        for (int i = t; i < 512; i += 256)
            prm[OFF_H5 + i] = s * ldf(b5, i, isf) + (be - m * s);
    }
    {
        float g = ldf(bn6p, 0, isf), be = ldf(bn6p, 1, isf);
        float m = ldf(bn6p, 2, isf), v = ldf(bn6p, 3, isf);
        float s = g * rsqrtf(v + 1e-5f);
        if (t == 0) prm[OFF_SC6] = s;
        for (int i = t; i < 512; i += 256)
            prm[OFF_H6 + i] = s * ldf(b6, i, isf) + (be - m * s);
    }
    {
        float g = ldf(bn7p, 0, isf), be = ldf(bn7p, 1, isf);
        float m = ldf(bn7p, 2, isf), v = ldf(bn7p, 3, isf);
        float s = g * rsqrtf(v + 1e-5f);
        if (t == 0) prm[OFF_SC7] = s;
        if (t < 128) prm[OFF_H7 + t] = s * ldf(b7, t, isf) + (be - m * s);
    }
    for (int i = t; i < 1024; i += 256) prm[OFF_W8 + i] = ldf(w8, i, isf);
    if (t < 8) prm[OFF_B8 + t] = ldf(b8, t, isf);
}

// ---------------------------------------------------------------------------
// conv1: transpose+bn0 -> conv1+bn1+relu.  One block per sample.
// Output PIXEL-MAJOR: c1[p][b][ic], bf16.
// ---------------------------------------------------------------------------
__global__ __launch_bounds__(256) void conv1_kernel(
    const float* __restrict__ xf, const float* __restrict__ prm,
    bf16_t* __restrict__ c1, int Bc)
{
    __shared__ float xn[180];
    __shared__ float w1s[576];

    const int t = threadIdx.x;
    const int b = blockIdx.x;
    const float s0 = prm[OFF_S0T0], t0 = prm[OFF_S0T0 + 1];

    for (int i = t; i < 576; i += 256) w1s[i] = prm[OFF_W1 + i];
    if (t < 180) {
        int row = t / 18, col = t - row * 18;
        float v = 0.f;
        if (row >= 1 && row <= 8 && col >= 1 && col <= 16)
            v = s0 * xf[(size_t)b * 128 + (col - 1) * 8 + (row - 1)] + t0;
        xn[t] = v;
    }
    __syncthreads();

    const int pg  = t & 31;
    const int oc0 = (t >> 5) * 8;

    float s1[8], h1[8];
    #pragma unroll
    for (int j = 0; j < 8; j++) {
        s1[j] = prm[OFF_S1 + oc0 + j];
        h1[j] = prm[OFF_H1 + oc0 + j];
    }
    #pragma unroll
    for (int m = 0; m < 4; m++) {
        int p = pg + 32 * m;
        int h = p >> 4, w = p & 15;
        float r[9];
        #pragma unroll
        for (int dh = 0; dh < 3; dh++)
            #pragma unroll
            for (int dw = 0; dw < 3; dw++)
                r[dh * 3 + dw] = xn[(h + dh) * 18 + (w + dw)];
        u16x8 o;
        #pragma unroll
        for (int j = 0; j < 8; j++) {
            float acc = 0.f;
            #pragma unroll
            for (int k = 0; k < 9; k++) acc += r[k] * w1s[(oc0 + j) * 9 + k];
            o[j] = f2b(fmaxf(s1[j] * acc + h1[j], 0.f));
        }
        *(u16x8*)(c1 + (size_t)p * Bc * 64 + (size_t)b * 64 + oc0) = o;
    }
}

// ---------------------------------------------------------------------------
// Fused MFMA: conv2(im2col GEMM K=576) + bn2relu -> lc3(K=64) + bn3relu
//             -> lc4(K=64) + bn4relu.  Grid (Bc/256, 128 pixels).
// BM=256 batch rows, N=64 oc.  4 waves stacked in M, each 64x64.
// Output bufA[b][p*64+oc] (fc5 consumes with permuted w5).
// ---------------------------------------------------------------------------
__global__ __launch_bounds__(256) void fused_mfma_kernel(
    const bf16_t* __restrict__ c1, const bf16_t* __restrict__ w2p,
    const bf16_t* __restrict__ w3p, const bf16_t* __restrict__ w4p,
    const float* __restrict__ prm, bf16_t* __restrict__ bufA, int Bc)
{
    __shared__ bf16_t smA[256 * 40];   // 20 KiB  staging A (256 rows x 32 k)
    __shared__ bf16_t smB[64 * 40];    //  5 KiB  staging W tile (64 x 32)
    __shared__ bf16_t smC[256 * 72];   // 36 KiB  activation tile [256][64] padded

    const int t    = threadIdx.x;
    const int lane = t & 63;
    const int wv   = t >> 6;
    const int m0   = blockIdx.x * 256;
    const int p    = blockIdx.y;
    const int h    = p >> 4, w = p & 15;

    const int fr = lane & 15;            // fragment row
    const int fq = (lane >> 4) * 8;      // fragment k-offset
    const int orow = (lane >> 4) * 4;    // C-layout row base
    const int ocol = lane & 15;          // C-layout col

    // staging coords
    const int sr = t >> 2;               // 0..63
    const int sq = (t & 3) * 8;          // 0,8,16,24

    f32x4 acc[4][4];
    #pragma unroll
    for (int i = 0; i < 4; i++)
        #pragma unroll
        for (int j = 0; j < 4; j++)
            acc[i][j] = (f32x4){0.f, 0.f, 0.f, 0.f};

    // ---------------- conv2: K = 576 (tap*64+ic), 18 k-steps ----------------
    for (int ks = 0; ks < 18; ks++) {
        const int tap = ks >> 1;
        const int dh = tap / 3 - 1, dw = tap % 3 - 1;
        const int hh = h + dh, ww = w + dw;
        if (hh < 0 || hh >= 8 || ww < 0 || ww >= 16) continue;   // block-uniform
        const int pp  = hh * 16 + ww;
        const int ic0 = (ks & 1) * 32;

        const bf16_t* abase = c1 + (size_t)pp * Bc * 64;
        #pragma unroll
        for (int u = 0; u < 4; u++) {
            const int row = sr + u * 64;
            *(uint4*)(smA + row * 40 + sq) =
                *(const uint4*)(abase + (size_t)(m0 + row) * 64 + ic0 + sq);
        }
        *(uint4*)(smB + sr * 40 + sq) =
            *(const uint4*)(w2p + sr * 576 + ks * 32 + sq);
        __syncthreads();

        bf16x8 af[4], bf[4];
        #pragma unroll
        for (int i = 0; i < 4; i++)
            af[i] = *(const bf16x8*)(smA + (wv * 64 + i * 16 + fr) * 40 + fq);
        #pragma unroll
        for (int j = 0; j < 4; j++)
            bf[j] = *(const bf16x8*)(smB + (j * 16 + fr) * 40 + fq);
        #pragma unroll
        for (int i = 0; i < 4; i++)
            #pragma unroll
            for (int j = 0; j < 4; j++)
                acc[i][j] = __builtin_amdgcn_mfma_f32_16x16x32_bf16(
                    af[i], bf[j], acc[i][j], 0, 0, 0);
        __syncthreads();
    }

    // conv2 epilogue: bn2 + relu -> smC [row][oc]
    #pragma unroll
    for (int j = 0; j < 4; j++) {
        const int oc = j * 16 + ocol;
        const float s = prm[OFF_S2 + oc], hh2 = prm[OFF_H2 + oc];
        #pragma unroll
        for (int i = 0; i < 4; i++) {
            const int rb = wv * 64 + i * 16 + orow;
            #pragma unroll
            for (int r = 0; r < 4; r++)
                smC[(rb + r) * 72 + oc] = f2b(fmaxf(s * acc[i][j][r] + hh2, 0.f));
        }
    }
    __syncthreads();

    // ---------------- lc3: K = 64, 2 k-steps ----------------
    #pragma unroll
    for (int i = 0; i < 4; i++)
        #pragma unroll
        for (int j = 0; j < 4; j++)
            acc[i][j] = (f32x4){0.f, 0.f, 0.f, 0.f};

    for (int ks = 0; ks < 2; ks++) {
        *(uint4*)(smB + sr * 40 + sq) =
            *(const uint4*)(w3p + (size_t)p * 4096 + sr * 64 + ks * 32 + sq);
        __syncthreads();
        bf16x8 af[4], bf[4];
        #pragma unroll
        for (int i = 0; i < 4; i++)
            af[i] = *(const bf16x8*)(smC + (wv * 64 + i * 16 + fr) * 72 + ks * 32 + fq);
        #pragma unroll
        for (int j = 0; j < 4; j++)
            bf[j] = *(const bf16x8*)(smB + (j * 16 + fr) * 40 + fq);
        #pragma unroll
        for (int i = 0; i < 4; i++)
            #pragma unroll
            for (int j = 0; j < 4; j++)
                acc[i][j] = __builtin_amdgcn_mfma_f32_16x16x32_bf16(
                    af[i], bf[j], acc[i][j], 0, 0, 0);
        __syncthreads();
    }

    // lc3 epilogue -> smC
    #pragma unroll
    for (int j = 0; j < 4; j++) {
        const int oc = j * 16 + ocol;
        const float s = prm[OFF_S3 + oc], hh3 = prm[OFF_H3 + oc];
        #pragma unroll
        for (int i = 0; i < 4; i++) {
            const int rb = wv * 64 + i * 16 + orow;
            #pragma unroll
            for (int r = 0; r < 4; r++)
                smC[(rb + r) * 72 + oc] = f2b(fmaxf(s * acc[i][j][r] + hh3, 0.f));
        }
    }
    __syncthreads();

    // ---------------- lc4: K = 64, 2 k-steps ----------------
    #pragma unroll
    for (int i = 0; i < 4; i++)
        #pragma unroll
        for (int j = 0; j < 4; j++)
            acc[i][j] = (f32x4){0.f, 0.f, 0.f, 0.f};

    for (int ks = 0; ks < 2; ks++) {
        *(uint4*)(smB + sr * 40 + sq) =
            *(const uint4*)(w4p + (size_t)p * 4096 + sr * 64 + ks * 32 + sq);
        __syncthreads();
        bf16x8 af[4], bf[4];
        #pragma unroll
        for (int i = 0; i < 4; i++)
            af[i] = *(const bf16x8*)(smC + (wv * 64 + i * 16 + fr) * 72 + ks * 32 + fq);
        #pragma unroll
        for (int j = 0; j < 4; j++)
            bf[j] = *(const bf16x8*)(smB + (j * 16 + fr) * 40 + fq);
        #pragma unroll
        for (int i = 0; i < 4; i++)
            #pragma unroll
            for (int j = 0; j < 4; j++)
                acc[i][j] = __builtin_amdgcn_mfma_f32_16x16x32_bf16(
                    af[i], bf[j], acc[i][j], 0, 0, 0);
        __syncthreads();
    }

    // lc4 epilogue -> smC, then coalesced write to bufA[b][p*64+oc]
    #pragma unroll
    for (int j = 0; j < 4; j++) {
        const int oc = j * 16 + ocol;
        const float s = prm[OFF_S4 + oc], hh4 = prm[OFF_H4 + oc];
        #pragma unroll
        for (int i = 0; i < 4; i++) {
            const int rb = wv * 64 + i * 16 + orow;
            #pragma unroll
            for (int r = 0; r < 4; r++)
                smC[(rb + r) * 72 + oc] = f2b(fmaxf(s * acc[i][j][r] + hh4, 0.f));
        }
    }
    __syncthreads();

    const int wrow = t >> 3, wc0 = (t & 7) * 8;
    #pragma unroll
    for (int pass = 0; pass < 8; pass++) {
        const int row = wrow + pass * 32;
        *(uint4*)(bufA + (size_t)(m0 + row) * 8192 + p * 64 + wc0) =
            *(const uint4*)(smC + row * 72 + wc0);
    }
}

// ---------------------------------------------------------------------------
// MFMA GEMM: out[M][N] = relu(scale * (A[M][K] . W[N][K]^T) + shift[n]), bf16.
// BM=BN=128, BK=32, 4 waves 2x2, each 64x64.  (unchanged from round 3)
// ---------------------------------------------------------------------------
__global__ __launch_bounds__(256) void gemm_mfma(
    const bf16_t* __restrict__ A, const bf16_t* __restrict__ W,
    const float* __restrict__ prm, int sc_off, int sh_off,
    bf16_t* __restrict__ out, int K, int N)
{
    __shared__ bf16_t As[128 * 40];
    __shared__ bf16_t Bs[128 * 40];
    const int t    = threadIdx.x;
    const int lane = t & 63;
    const int w    = t >> 6;
    const int wr   = w >> 1, wc = w & 1;
    const int m0   = blockIdx.x * 128, n0 = blockIdx.y * 128;

    const int r0 = t >> 2, q0 = (t & 3) * 8;
    const int r1 = r0 + 64;

    f32x4 acc[4][4];
    #pragma unroll
    for (int i = 0; i < 4; i++)
        #pragma unroll
        for (int j = 0; j < 4; j++)
            acc[i][j] = (f32x4){0.f, 0.f, 0.f, 0.f};

    const int fr = lane & 15;
    const int fq = (lane >> 4) * 8;

    for (int k0 = 0; k0 < K; k0 += 32) {
        const uint4 a0v = *(const uint4*)(A + (size_t)(m0 + r0) * K + k0 + q0);
        const uint4 a1v = *(const uint4*)(A + (size_t)(m0 + r1) * K + k0 + q0);
        const uint4 b0v = *(const uint4*)(W + (size_t)(n0 + r0) * K + k0 + q0);
        const uint4 b1v = *(const uint4*)(W + (size_t)(n0 + r1) * K + k0 + q0);
        *(uint4*)(As + r0 * 40 + q0) = a0v;
        *(uint4*)(As + r1 * 40 + q0) = a1v;
        *(uint4*)(Bs + r0 * 40 + q0) = b0v;
        *(uint4*)(Bs + r1 * 40 + q0) = b1v;
        __syncthreads();

        bf16x8 af[4], bfr[4];
        #pragma unroll
        for (int i = 0; i < 4; i++) {
            af[i]  = *(const bf16x8*)(As + (wr * 64 + i * 16 + fr) * 40 + fq);
            bfr[i] = *(const bf16x8*)(Bs + (wc * 64 + i * 16 + fr) * 40 + fq);
        }
        #pragma unroll
        for (int i = 0; i < 4; i++)
            #pragma unroll
            for (int j = 0; j < 4; j++)
                acc[i][j] = __builtin_amdgcn_mfma_f32_16x16x32_bf16(
                    af[i], bfr[j], acc[i][j], 0, 0, 0);
        __syncthreads();
    }

    const float s    = prm[sc_off];
    const int   orow = (lane >> 4) * 4;
    const int   ocol = lane & 15;
    #pragma unroll
    for (int j = 0; j < 4; j++) {
        const int n  = n0 + wc * 64 + j * 16 + ocol;
        const float sh = prm[sh_off + n];
        #pragma unroll
        for (int i = 0; i < 4; i++) {
            const int mb = m0 + wr * 64 + i * 16 + orow;
            #pragma unroll
            for (int r = 0; r < 4; r++) {
                float v = fmaxf(s * acc[i][j][r] + sh, 0.f);
                out[(size_t)(mb + r) * N + n] = f2b(v);
            }
        }
    }
}

// ---------------------------------------------------------------------------
// fc8: out[b][n] = h[b][:] . w8[n][:] + b8[n]   (N=8, K=128), h is bf16
// ---------------------------------------------------------------------------
__global__ __launch_bounds__(256) void fc8_kernel(
    const bf16_t* __restrict__ h, const float* __restrict__ prm,
    void* __restrict__ out, int c0)
{
    __shared__ float wsm[8 * 129];
    const int t = threadIdx.x;
    for (int i = t; i < 1024; i += 256) {
        int n = i >> 7, k = i & 127;
        wsm[n * 129 + k] = prm[OFF_W8 + i];
    }
    __syncthreads();
    const int isf = prm[OFF_FLAG] > 0.5f;
    const int bl = t >> 3, n = t & 7;
    const int b = c0 + blockIdx.x * 32 + bl;
    const bf16_t* hb = h + (size_t)(blockIdx.x * 32 + bl) * 128;
    float acc = prm[OFF_B8 + n];
    for (int k = 0; k < 128; k++) acc += b2f(hb[k]) * wsm[n * 129 + k];
    if (isf) ((float*)out)[(size_t)b * 8 + n] = acc;
    else     ((bf16_t*)out)[(size_t)b * 8 + n] = f2b(acc);
}

// ---------------------------------------------------------------------------
extern "C" void kernel_launch(void* const* d_in, const int* in_sizes, int n_in,
                              void* d_out, int out_size, void* d_ws, size_t ws_size,
                              hipStream_t stream)
{
    const void* x    = d_in[0];
    const void* bn0p = d_in[1];
    const void* w1   = d_in[2];
    const void* b1   = d_in[3];
    const void* bn1p = d_in[4];
    const void* w2   = d_in[5];
    const void* b2c  = d_in[6];
    const void* bn2p = d_in[7];
    const void* w3   = d_in[8];
    const void* bn3p = d_in[9];
    const void* w4   = d_in[10];
    const void* bn4p = d_in[11];
    const void* w5   = d_in[12];
    const void* b5   = d_in[13];
    const void* bn5p = d_in[14];
    const void* w6   = d_in[15];
    const void* b6   = d_in[16];
    const void* bn6p = d_in[17];
    const void* w7   = d_in[18];
    const void* b7   = d_in[19];
    const void* bn7p = d_in[20];
    const void* w8   = d_in[21];
    const void* b8   = d_in[22];

    char* base = (char*)d_ws;
    float*  prm = (float*)(base + 0);            //    16384 B
    float*  xf  = (float*)(base + 16384);        //  4194304 B
    bf16_t* w2p = (bf16_t*)(base + 4210688);     //    73728 B
    bf16_t* w3p = (bf16_t*)(base + 4284416);     //  1048576 B
    bf16_t* w4p = (bf16_t*)(base + 5332992);     //  1048576 B
    bf16_t* w5p = (bf16_t*)(base + 6381568);     //  8388608 B
    bf16_t* w6b = (bf16_t*)(base + 14770176);    //   524288 B
    bf16_t* w7b = (bf16_t*)(base + 15294464);    //   131072 B
    char*   acts = base + 15425536;

    const int B = 8192;
    const size_t FIXED = 15425536ull;
    size_t avail = (ws_size > FIXED) ? (ws_size - FIXED) : 0;
    // per-sample: c1 16384 + bufA 16384 + bufC 1024 + bufD 1024 + bufE 256 = 35072
    int Bc = 8192;
    while (Bc > 256 && (size_t)Bc * 35072ull > avail) Bc >>= 1;

    bf16_t* c1   = (bf16_t*)acts;                    // [128][Bc][64]
    bf16_t* bufA = c1 + (size_t)Bc * 8192;           // [Bc][8192]
    bf16_t* bufC = bufA + (size_t)Bc * 8192;         // [Bc][512]
    bf16_t* bufD = bufC + (size_t)Bc * 512;          // [Bc][512]
    bf16_t* bufE = bufD + (size_t)Bc * 512;          // [Bc][128]

    detect_kernel<<<1, 64, 0, stream>>>(x, prm);
    fold_params_kernel<<<1, 256, 0, stream>>>(
        bn0p, w1, b1, bn1p, b2c, bn2p, bn3p, bn4p,
        b5, bn5p, b6, bn6p, b7, bn7p, w8, b8, prm);

    cvt_kernel<<<(1048576 + 255) / 256, 256, 0, stream>>>(x, xf, 1048576, prm);
    pw2_kernel<<<(36864 + 255) / 256, 256, 0, stream>>>(w2, w2p, prm);
    pw34_kernel<<<(524288 + 255) / 256, 256, 0, stream>>>(w3, w3p, prm);
    pw34_kernel<<<(524288 + 255) / 256, 256, 0, stream>>>(w4, w4p, prm);
    pw5_kernel<<<(4194304 + 255) / 256, 256, 0, stream>>>(w5, w5p, prm);
    cvtb_kernel<<<(262144 + 255) / 256, 256, 0, stream>>>(w6, w6b, 262144, prm);
    cvtb_kernel<<<(65536 + 255) / 256, 256, 0, stream>>>(w7, w7b, 65536, prm);

    for (int c0 = 0; c0 < B; c0 += Bc) {
        conv1_kernel<<<Bc, 256, 0, stream>>>(
            xf + (size_t)c0 * 128, prm, c1, Bc);
        fused_mfma_kernel<<<dim3(Bc / 256, 128), 256, 0, stream>>>(
            c1, w2p, w3p, w4p, prm, bufA, Bc);
        gemm_mfma<<<dim3(Bc / 128, 4), 256, 0, stream>>>(
            bufA, w5p, prm, OFF_SC5, OFF_H5, bufC, 8192, 512);
        gemm_mfma<<<dim3(Bc / 128, 4), 256, 0, stream>>>(
            bufC, w6b, prm, OFF_SC6, OFF_H6, bufD, 512, 512);
        gemm_mfma<<<dim3(Bc / 128, 1), 256, 0, stream>>>(
            bufD, w7b, prm, OFF_SC7, OFF_H7, bufE, 512, 128);
        fc8_kernel<<<Bc / 32, 256, 0, stream>>>(bufE, prm, d_out, c0);
    }
}

// Round 5
// 585.941 us; speedup vs baseline: 7.6543x; 1.3782x over previous
//
#include <hip/hip_runtime.h>

typedef unsigned short bf16_t;
typedef __attribute__((ext_vector_type(8))) short bf16x8;
typedef __attribute__((ext_vector_type(8))) unsigned short u16x8;
typedef __attribute__((ext_vector_type(4))) float f32x4;

#if defined(__has_builtin)
#if __has_builtin(__builtin_amdgcn_global_load_lds)
#define HAS_GLL 1
#endif
#endif

__device__ __forceinline__ float b2f(bf16_t u) {
    return __uint_as_float(((unsigned int)u) << 16);
}
__device__ __forceinline__ bf16_t f2b(float f) {
    unsigned int x = __float_as_uint(f);
    unsigned int r = x + 0x7fffu + ((x >> 16) & 1u);
    return (bf16_t)(r >> 16);
}
__device__ __forceinline__ float ldf(const void* p, int i, int isf) {
    return isf ? ((const float*)p)[i] : b2f(((const bf16_t*)p)[i]);
}

#ifdef HAS_GLL
// async 16B global->LDS; lds dest = wave-uniform base + lane*16
__device__ __forceinline__ void gll16(const bf16_t* g, bf16_t* l) {
    __builtin_amdgcn_global_load_lds(
        (const __attribute__((address_space(1))) unsigned int*)g,
        (__attribute__((address_space(3))) unsigned int*)l,
        16, 0, 0);
}
#endif

// ---- params block offsets (floats) ----
#define OFF_S0T0 0
#define OFF_W1   16
#define OFF_S1   592
#define OFF_H1   656
#define OFF_S2   720
#define OFF_H2   784
#define OFF_S3   848
#define OFF_H3   912
#define OFF_S4   976
#define OFF_H4   1040
#define OFF_SC5  1104
#define OFF_H5   1112
#define OFF_SC6  1624
#define OFF_H6   1632
#define OFF_SC7  2144
#define OFF_H7   2152
#define OFF_W8   2280
#define OFF_B8   3304
#define OFF_FLAG 4032

// ---------------------------------------------------------------------------
// dtype detector (bf16 vs fp32 storage), statistical on N(0,1) input x.
// ---------------------------------------------------------------------------
__global__ void detect_kernel(const void* xraw, float* prm)
{
    if (threadIdx.x == 0 && blockIdx.x == 0) {
        const unsigned int* w = (const unsigned int*)xraw;
        int good = 0;
        for (int i = 0; i < 64; i++) {
            float f = __uint_as_float(w[i] << 16);
            float a = fabsf(f);
            if (a >= 0.0009765625f && a <= 16.0f) good++;
        }
        prm[OFF_FLAG] = (good >= 32) ? 0.0f : 1.0f;  // many good => bf16
    }
}

__global__ __launch_bounds__(256) void cvt_kernel(
    const void* __restrict__ src, float* __restrict__ dst, int n,
    const float* __restrict__ prm)
{
    const int isf = prm[OFF_FLAG] > 0.5f;
    int i = blockIdx.x * 256 + threadIdx.x;
    if (i < n) dst[i] = ldf(src, i, isf);
}

__global__ __launch_bounds__(256) void cvtb_kernel(
    const void* __restrict__ src, bf16_t* __restrict__ dst, int n,
    const float* __restrict__ prm)
{
    const int isf = prm[OFF_FLAG] > 0.5f;
    int i = blockIdx.x * 256 + threadIdx.x;
    if (i < n) dst[i] = isf ? f2b(((const float*)src)[i]) : ((const bf16_t*)src)[i];
}

// w2 [oc][ic][tap] -> w2p [oc][tap*64+ic]
__global__ __launch_bounds__(256) void pw2_kernel(
    const void* __restrict__ src, bf16_t* __restrict__ dst,
    const float* __restrict__ prm)
{
    const int isf = prm[OFF_FLAG] > 0.5f;
    int i = blockIdx.x * 256 + threadIdx.x;
    if (i >= 36864) return;
    int oc = i / 576, r = i - oc * 576;
    int tap = r >> 6, ic = r & 63;
    dst[i] = f2b(ldf(src, oc * 576 + ic * 9 + tap, isf));
}

// w3/w4 [oc][ic][p] -> [p][oc*64+ic]
__global__ __launch_bounds__(256) void pw34_kernel(
    const void* __restrict__ src, bf16_t* __restrict__ dst,
    const float* __restrict__ prm)
{
    const int isf = prm[OFF_FLAG] > 0.5f;
    int i = blockIdx.x * 256 + threadIdx.x;
    if (i >= 524288) return;
    int p = i >> 12, r = i & 4095;
    int oc = r >> 6, ic = r & 63;
    dst[i] = f2b(ldf(src, oc * 8192 + ic * 128 + p, isf));
}

// w5 [n][c*128+p] -> w5p [n][p*64+c]
__global__ __launch_bounds__(256) void pw5_kernel(
    const void* __restrict__ src, bf16_t* __restrict__ dst,
    const float* __restrict__ prm)
{
    const int isf = prm[OFF_FLAG] > 0.5f;
    int i = blockIdx.x * 256 + threadIdx.x;
    if (i >= 4194304) return;
    int nr = i >> 13, r = i & 8191;
    int p = r >> 6, c = r & 63;
    dst[i] = f2b(ldf(src, nr * 8192 + c * 128 + p, isf));
}

// fold all small tensors + BN params into the fp32 params block
__global__ __launch_bounds__(256) void fold_params_kernel(
    const void* bn0p, const void* w1, const void* b1, const void* bn1p,
    const void* b2c, const void* bn2p, const void* bn3p, const void* bn4p,
    const void* b5, const void* bn5p, const void* b6, const void* bn6p,
    const void* b7, const void* bn7p, const void* w8, const void* b8,
    float* prm)
{
    const int isf = prm[OFF_FLAG] > 0.5f;
    const int t = threadIdx.x;

    if (t == 0) {
        float g = ldf(bn0p, 0, isf), be = ldf(bn0p, 1, isf);
        float m = ldf(bn0p, 2, isf), v = ldf(bn0p, 3, isf);
        float s = g * rsqrtf(v + 1e-5f);
        prm[OFF_S0T0] = s; prm[OFF_S0T0 + 1] = be - m * s;
    }
    for (int i = t; i < 576; i += 256) prm[OFF_W1 + i] = ldf(w1, i, isf);

    if (t < 64) {
        {
            float g = ldf(bn1p, t, isf), be = ldf(bn1p, 64 + t, isf);
            float m = ldf(bn1p, 128 + t, isf), v = ldf(bn1p, 192 + t, isf);
            float s = g * rsqrtf(v + 1e-5f);
            prm[OFF_S1 + t] = s;
            prm[OFF_H1 + t] = s * ldf(b1, t, isf) + (be - m * s);
        }
        {
            float g = ldf(bn2p, t, isf), be = ldf(bn2p, 64 + t, isf);
            float m = ldf(bn2p, 128 + t, isf), v = ldf(bn2p, 192 + t, isf);
            float s = g * rsqrtf(v + 1e-5f);
            prm[OFF_S2 + t] = s;
            prm[OFF_H2 + t] = s * ldf(b2c, t, isf) + (be - m * s);
        }
        {
            float g = ldf(bn3p, t, isf), be = ldf(bn3p, 64 + t, isf);
            float m = ldf(bn3p, 128 + t, isf), v = ldf(bn3p, 192 + t, isf);
            float s = g * rsqrtf(v + 1e-5f);
            prm[OFF_S3 + t] = s;
            prm[OFF_H3 + t] = be - m * s;
        }
        {
            float g = ldf(bn4p, t, isf), be = ldf(bn4p, 64 + t, isf);
            float m = ldf(bn4p, 128 + t, isf), v = ldf(bn4p, 192 + t, isf);
            float s = g * rsqrtf(v + 1e-5f);
            prm[OFF_S4 + t] = s;
            prm[OFF_H4 + t] = be - m * s;
        }
    }
    {
        float g = ldf(bn5p, 0, isf), be = ldf(bn5p, 1, isf);
        float m = ldf(bn5p, 2, isf), v = ldf(bn5p, 3, isf);
        float s = g * rsqrtf(v + 1e-5f);
        if (t == 0) prm[OFF_SC5] = s;
        for (int i = t; i < 512; i += 256)
            prm[OFF_H5 + i] = s * ldf(b5, i, isf) + (be - m * s);
    }
    {
        float g = ldf(bn6p, 0, isf), be = ldf(bn6p, 1, isf);
        float m = ldf(bn6p, 2, isf), v = ldf(bn6p, 3, isf);
        float s = g * rsqrtf(v + 1e-5f);
        if (t == 0) prm[OFF_SC6] = s;
        for (int i = t; i < 512; i += 256)
            prm[OFF_H6 + i] = s * ldf(b6, i, isf) + (be - m * s);
    }
    {
        float g = ldf(bn7p, 0, isf), be = ldf(bn7p, 1, isf);
        float m = ldf(bn7p, 2, isf), v = ldf(bn7p, 3, isf);
        float s = g * rsqrtf(v + 1e-5f);
        if (t == 0) prm[OFF_SC7] = s;
        if (t < 128) prm[OFF_H7 + t] = s * ldf(b7, t, isf) + (be - m * s);
    }
    for (int i = t; i < 1024; i += 256) prm[OFF_W8 + i] = ldf(w8, i, isf);
    if (t < 8) prm[OFF_B8 + t] = ldf(b8, t, isf);
}

// ---------------------------------------------------------------------------
// conv1: transpose+bn0 -> conv1+bn1+relu.  One block per sample.
// Output PIXEL-MAJOR: c1[p][b][ic], bf16.
// ---------------------------------------------------------------------------
__global__ __launch_bounds__(256) void conv1_kernel(
    const float* __restrict__ xf, const float* __restrict__ prm,
    bf16_t* __restrict__ c1, int Bc)
{
    __shared__ float xn[180];
    __shared__ float w1s[576];

    const int t = threadIdx.x;
    const int b = blockIdx.x;
    const float s0 = prm[OFF_S0T0], t0 = prm[OFF_S0T0 + 1];

    for (int i = t; i < 576; i += 256) w1s[i] = prm[OFF_W1 + i];
    if (t < 180) {
        int row = t / 18, col = t - row * 18;
        float v = 0.f;
        if (row >= 1 && row <= 8 && col >= 1 && col <= 16)
            v = s0 * xf[(size_t)b * 128 + (col - 1) * 8 + (row - 1)] + t0;
        xn[t] = v;
    }
    __syncthreads();

    const int pg  = t & 31;
    const int oc0 = (t >> 5) * 8;

    float s1[8], h1[8];
    #pragma unroll
    for (int j = 0; j < 8; j++) {
        s1[j] = prm[OFF_S1 + oc0 + j];
        h1[j] = prm[OFF_H1 + oc0 + j];
    }
    #pragma unroll
    for (int m = 0; m < 4; m++) {
        int p = pg + 32 * m;
        int h = p >> 4, w = p & 15;
        float r[9];
        #pragma unroll
        for (int dh = 0; dh < 3; dh++)
            #pragma unroll
            for (int dw = 0; dw < 3; dw++)
                r[dh * 3 + dw] = xn[(h + dh) * 18 + (w + dw)];
        u16x8 o;
        #pragma unroll
        for (int j = 0; j < 8; j++) {
            float acc = 0.f;
            #pragma unroll
            for (int k = 0; k < 9; k++) acc += r[k] * w1s[(oc0 + j) * 9 + k];
            o[j] = f2b(fmaxf(s1[j] * acc + h1[j], 0.f));
        }
        *(u16x8*)(c1 + (size_t)p * Bc * 64 + (size_t)b * 64 + oc0) = o;
    }
}

// ---------------------------------------------------------------------------
// Fused MFMA: conv2(im2col GEMM K=576) + bn2relu -> lc3(K=64) + bn3relu
//             -> lc4(K=64) + bn4relu.  Grid (Bc/256, 128 pixels).
// ---------------------------------------------------------------------------
__global__ __launch_bounds__(256) void fused_mfma_kernel(
    const bf16_t* __restrict__ c1, const bf16_t* __restrict__ w2p,
    const bf16_t* __restrict__ w3p, const bf16_t* __restrict__ w4p,
    const float* __restrict__ prm, bf16_t* __restrict__ bufA, int Bc)
{
    __shared__ bf16_t smA[256 * 40];   // 20 KiB
    __shared__ bf16_t smB[64 * 40];    //  5 KiB
    __shared__ bf16_t smC[256 * 72];   // 36 KiB

    const int t    = threadIdx.x;
    const int lane = t & 63;
    const int wv   = t >> 6;
    const int m0   = blockIdx.x * 256;
    const int p    = blockIdx.y;
    const int h    = p >> 4, w = p & 15;

    const int fr = lane & 15;
    const int fq = (lane >> 4) * 8;
    const int orow = (lane >> 4) * 4;
    const int ocol = lane & 15;

    const int sr = t >> 2;
    const int sq = (t & 3) * 8;

    f32x4 acc[4][4];
    #pragma unroll
    for (int i = 0; i < 4; i++)
        #pragma unroll
        for (int j = 0; j < 4; j++)
            acc[i][j] = (f32x4){0.f, 0.f, 0.f, 0.f};

    // ---------------- conv2: K = 576 (tap*64+ic), 18 k-steps ----------------
    for (int ks = 0; ks < 18; ks++) {
        const int tap = ks >> 1;
        const int dh = tap / 3 - 1, dw = tap % 3 - 1;
        const int hh = h + dh, ww = w + dw;
        if (hh < 0 || hh >= 8 || ww < 0 || ww >= 16) continue;   // block-uniform
        const int pp  = hh * 16 + ww;
        const int ic0 = (ks & 1) * 32;

        const bf16_t* abase = c1 + (size_t)pp * Bc * 64;
        #pragma unroll
        for (int u = 0; u < 4; u++) {
            const int row = sr + u * 64;
            *(uint4*)(smA + row * 40 + sq) =
                *(const uint4*)(abase + (size_t)(m0 + row) * 64 + ic0 + sq);
        }
        *(uint4*)(smB + sr * 40 + sq) =
            *(const uint4*)(w2p + sr * 576 + ks * 32 + sq);
        __syncthreads();

        bf16x8 af[4], bf[4];
        #pragma unroll
        for (int i = 0; i < 4; i++)
            af[i] = *(const bf16x8*)(smA + (wv * 64 + i * 16 + fr) * 40 + fq);
        #pragma unroll
        for (int j = 0; j < 4; j++)
            bf[j] = *(const bf16x8*)(smB + (j * 16 + fr) * 40 + fq);
        #pragma unroll
        for (int i = 0; i < 4; i++)
            #pragma unroll
            for (int j = 0; j < 4; j++)
                acc[i][j] = __builtin_amdgcn_mfma_f32_16x16x32_bf16(
                    af[i], bf[j], acc[i][j], 0, 0, 0);
        __syncthreads();
    }

    // conv2 epilogue -> smC
    #pragma unroll
    for (int j = 0; j < 4; j++) {
        const int oc = j * 16 + ocol;
        const float s = prm[OFF_S2 + oc], hh2 = prm[OFF_H2 + oc];
        #pragma unroll
        for (int i = 0; i < 4; i++) {
            const int rb = wv * 64 + i * 16 + orow;
            #pragma unroll
            for (int r = 0; r < 4; r++)
                smC[(rb + r) * 72 + oc] = f2b(fmaxf(s * acc[i][j][r] + hh2, 0.f));
        }
    }
    __syncthreads();

    // ---------------- lc3: K = 64 ----------------
    #pragma unroll
    for (int i = 0; i < 4; i++)
        #pragma unroll
        for (int j = 0; j < 4; j++)
            acc[i][j] = (f32x4){0.f, 0.f, 0.f, 0.f};

    for (int ks = 0; ks < 2; ks++) {
        *(uint4*)(smB + sr * 40 + sq) =
            *(const uint4*)(w3p + (size_t)p * 4096 + sr * 64 + ks * 32 + sq);
        __syncthreads();
        bf16x8 af[4], bf[4];
        #pragma unroll
        for (int i = 0; i < 4; i++)
            af[i] = *(const bf16x8*)(smC + (wv * 64 + i * 16 + fr) * 72 + ks * 32 + fq);
        #pragma unroll
        for (int j = 0; j < 4; j++)
            bf[j] = *(const bf16x8*)(smB + (j * 16 + fr) * 40 + fq);
        #pragma unroll
        for (int i = 0; i < 4; i++)
            #pragma unroll
            for (int j = 0; j < 4; j++)
                acc[i][j] = __builtin_amdgcn_mfma_f32_16x16x32_bf16(
                    af[i], bf[j], acc[i][j], 0, 0, 0);
        __syncthreads();
    }

    #pragma unroll
    for (int j = 0; j < 4; j++) {
        const int oc = j * 16 + ocol;
        const float s = prm[OFF_S3 + oc], hh3 = prm[OFF_H3 + oc];
        #pragma unroll
        for (int i = 0; i < 4; i++) {
            const int rb = wv * 64 + i * 16 + orow;
            #pragma unroll
            for (int r = 0; r < 4; r++)
                smC[(rb + r) * 72 + oc] = f2b(fmaxf(s * acc[i][j][r] + hh3, 0.f));
        }
    }
    __syncthreads();

    // ---------------- lc4: K = 64 ----------------
    #pragma unroll
    for (int i = 0; i < 4; i++)
        #pragma unroll
        for (int j = 0; j < 4; j++)
            acc[i][j] = (f32x4){0.f, 0.f, 0.f, 0.f};

    for (int ks = 0; ks < 2; ks++) {
        *(uint4*)(smB + sr * 40 + sq) =
            *(const uint4*)(w4p + (size_t)p * 4096 + sr * 64 + ks * 32 + sq);
        __syncthreads();
        bf16x8 af[4], bf[4];
        #pragma unroll
        for (int i = 0; i < 4; i++)
            af[i] = *(const bf16x8*)(smC + (wv * 64 + i * 16 + fr) * 72 + ks * 32 + fq);
        #pragma unroll
        for (int j = 0; j < 4; j++)
            bf[j] = *(const bf16x8*)(smB + (j * 16 + fr) * 40 + fq);
        #pragma unroll
        for (int i = 0; i < 4; i++)
            #pragma unroll
            for (int j = 0; j < 4; j++)
                acc[i][j] = __builtin_amdgcn_mfma_f32_16x16x32_bf16(
                    af[i], bf[j], acc[i][j], 0, 0, 0);
        __syncthreads();
    }

    #pragma unroll
    for (int j = 0; j < 4; j++) {
        const int oc = j * 16 + ocol;
        const float s = prm[OFF_S4 + oc], hh4 = prm[OFF_H4 + oc];
        #pragma unroll
        for (int i = 0; i < 4; i++) {
            const int rb = wv * 64 + i * 16 + orow;
            #pragma unroll
            for (int r = 0; r < 4; r++)
                smC[(rb + r) * 72 + oc] = f2b(fmaxf(s * acc[i][j][r] + hh4, 0.f));
        }
    }
    __syncthreads();

    const int wrow = t >> 3, wc0 = (t & 7) * 8;
    #pragma unroll
    for (int pass = 0; pass < 8; pass++) {
        const int row = wrow + pass * 32;
        *(uint4*)(bufA + (size_t)(m0 + row) * 8192 + p * 64 + wc0) =
            *(const uint4*)(smC + row * 72 + wc0);
    }
}

// ---------------------------------------------------------------------------
// MFMA GEMM (m97-style): out[M][N] = relu(s*(A.W^T)+shift), bf16.
// BM=BN=128, BK=32, 4 waves 2x2, wave tile 64x64.  UNPADDED LDS tiles,
// async global_load_lds width-16 staging (wave-contiguous chunk order).
// ---------------------------------------------------------------------------
__global__ __launch_bounds__(256) void gemm_mfma(
    const bf16_t* __restrict__ A, const bf16_t* __restrict__ W,
    const float* __restrict__ prm, int sc_off, int sh_off,
    bf16_t* __restrict__ out, int K, int N)
{
    __shared__ bf16_t As[128 * 32];    // 8 KiB, row-major [row][k]
    __shared__ bf16_t Bs[128 * 32];    // 8 KiB
    const int t    = threadIdx.x;
    const int lane = t & 63;
    const int wv   = t >> 6;
    const int wr   = wv >> 1, wc = wv & 1;
    const int m0   = blockIdx.x * 128, n0 = blockIdx.y * 128;

    // chunk c = wv*64 + lane covers LDS bytes [16c,16c+16) = (row=c>>2, k=(c&3)*8)
    // second chunk c+256 covers rows 64..127 at same k offset.
    const int ci = wv * 64 + lane;
    const int r0 = ci >> 2, q0 = (ci & 3) * 8;

    const bf16_t* gA0 = A + (size_t)(m0 + r0) * K + q0;
    const bf16_t* gA1 = A + (size_t)(m0 + r0 + 64) * K + q0;
    const bf16_t* gB0 = W + (size_t)(n0 + r0) * K + q0;
    const bf16_t* gB1 = W + (size_t)(n0 + r0 + 64) * K + q0;
    bf16_t* lA0 = As + ci * 8;
    bf16_t* lA1 = As + (ci + 256) * 8;
    bf16_t* lB0 = Bs + ci * 8;
    bf16_t* lB1 = Bs + (ci + 256) * 8;

    f32x4 acc[4][4];
    #pragma unroll
    for (int i = 0; i < 4; i++)
        #pragma unroll
        for (int j = 0; j < 4; j++)
            acc[i][j] = (f32x4){0.f, 0.f, 0.f, 0.f};

    const int fr = lane & 15;
    const int fq = (lane >> 4) * 8;

    for (int k0 = 0; k0 < K; k0 += 32) {
#ifdef HAS_GLL
        gll16(gA0 + k0, lA0);
        gll16(gA1 + k0, lA1);
        gll16(gB0 + k0, lB0);
        gll16(gB1 + k0, lB1);
#else
        *(uint4*)lA0 = *(const uint4*)(gA0 + k0);
        *(uint4*)lA1 = *(const uint4*)(gA1 + k0);
        *(uint4*)lB0 = *(const uint4*)(gB0 + k0);
        *(uint4*)lB1 = *(const uint4*)(gB1 + k0);
#endif
        __syncthreads();

        bf16x8 af[4], bfr[4];
        #pragma unroll
        for (int i = 0; i < 4; i++) {
            af[i]  = *(const bf16x8*)(As + (wr * 64 + i * 16 + fr) * 32 + fq);
            bfr[i] = *(const bf16x8*)(Bs + (wc * 64 + i * 16 + fr) * 32 + fq);
        }
        #pragma unroll
        for (int i = 0; i < 4; i++)
            #pragma unroll
            for (int j = 0; j < 4; j++)
                acc[i][j] = __builtin_amdgcn_mfma_f32_16x16x32_bf16(
                    af[i], bfr[j], acc[i][j], 0, 0, 0);
        __syncthreads();
    }

    const float s    = prm[sc_off];
    const int   orow = (lane >> 4) * 4;
    const int   ocol = lane & 15;
    #pragma unroll
    for (int j = 0; j < 4; j++) {
        const int n  = n0 + wc * 64 + j * 16 + ocol;
        const float sh = prm[sh_off + n];
        #pragma unroll
        for (int i = 0; i < 4; i++) {
            const int mb = m0 + wr * 64 + i * 16 + orow;
            #pragma unroll
            for (int r = 0; r < 4; r++) {
                float v = fmaxf(s * acc[i][j][r] + sh, 0.f);
                out[(size_t)(mb + r) * N + n] = f2b(v);
            }
        }
    }
}

// ---------------------------------------------------------------------------
// fc8: out[b][n] = h[b][:] . w8[n][:] + b8[n]   (N=8, K=128), h is bf16
// ---------------------------------------------------------------------------
__global__ __launch_bounds__(256) void fc8_kernel(
    const bf16_t* __restrict__ h, const float* __restrict__ prm,
    void* __restrict__ out, int c0)
{
    __shared__ float wsm[8 * 129];
    const int t = threadIdx.x;
    for (int i = t; i < 1024; i += 256) {
        int n = i >> 7, k = i & 127;
        wsm[n * 129 + k] = prm[OFF_W8 + i];
    }
    __syncthreads();
    const int isf = prm[OFF_FLAG] > 0.5f;
    const int bl = t >> 3, n = t & 7;
    const int b = c0 + blockIdx.x * 32 + bl;
    const bf16_t* hb = h + (size_t)(blockIdx.x * 32 + bl) * 128;
    float acc = prm[OFF_B8 + n];
    for (int k = 0; k < 128; k++) acc += b2f(hb[k]) * wsm[n * 129 + k];
    if (isf) ((float*)out)[(size_t)b * 8 + n] = acc;
    else     ((bf16_t*)out)[(size_t)b * 8 + n] = f2b(acc);
}

// ---------------------------------------------------------------------------
extern "C" void kernel_launch(void* const* d_in, const int* in_sizes, int n_in,
                              void* d_out, int out_size, void* d_ws, size_t ws_size,
                              hipStream_t stream)
{
    const void* x    = d_in[0];
    const void* bn0p = d_in[1];
    const void* w1   = d_in[2];
    const void* b1   = d_in[3];
    const void* bn1p = d_in[4];
    const void* w2   = d_in[5];
    const void* b2c  = d_in[6];
    const void* bn2p = d_in[7];
    const void* w3   = d_in[8];
    const void* bn3p = d_in[9];
    const void* w4   = d_in[10];
    const void* bn4p = d_in[11];
    const void* w5   = d_in[12];
    const void* b5   = d_in[13];
    const void* bn5p = d_in[14];
    const void* w6   = d_in[15];
    const void* b6   = d_in[16];
    const void* bn6p = d_in[17];
    const void* w7   = d_in[18];
    const void* b7   = d_in[19];
    const void* bn7p = d_in[20];
    const void* w8   = d_in[21];
    const void* b8   = d_in[22];

    char* base = (char*)d_ws;
    float*  prm = (float*)(base + 0);            //    16384 B
    float*  xf  = (float*)(base + 16384);        //  4194304 B
    bf16_t* w2p = (bf16_t*)(base + 4210688);     //    73728 B
    bf16_t* w3p = (bf16_t*)(base + 4284416);     //  1048576 B
    bf16_t* w4p = (bf16_t*)(base + 5332992);     //  1048576 B
    bf16_t* w5p = (bf16_t*)(base + 6381568);     //  8388608 B
    bf16_t* w6b = (bf16_t*)(base + 14770176);    //   524288 B
    bf16_t* w7b = (bf16_t*)(base + 15294464);    //   131072 B
    char*   acts = base + 15425536;

    const int B = 8192;
    const size_t FIXED = 15425536ull;

    detect_kernel<<<1, 64, 0, stream>>>(x, prm);
    fold_params_kernel<<<1, 256, 0, stream>>>(
        bn0p, w1, b1, bn1p, b2c, bn2p, bn3p, bn4p,
        b5, bn5p, b6, bn6p, b7, bn7p, w8, b8, prm);

    cvt_kernel<<<(1048576 + 255) / 256, 256, 0, stream>>>(x, xf, 1048576, prm);
    pw2_kernel<<<(36864 + 255) / 256, 256, 0, stream>>>(w2, w2p, prm);
    pw34_kernel<<<(524288 + 255) / 256, 256, 0, stream>>>(w3, w3p, prm);
    pw34_kernel<<<(524288 + 255) / 256, 256, 0, stream>>>(w4, w4p, prm);
    pw5_kernel<<<(4194304 + 255) / 256, 256, 0, stream>>>(w5, w5p, prm);
    cvtb_kernel<<<(262144 + 255) / 256, 256, 0, stream>>>(w6, w6b, 262144, prm);
    cvtb_kernel<<<(65536 + 255) / 256, 256, 0, stream>>>(w7, w7b, 65536, prm);

    // Full-batch fc path: c1 chunked (Bf) + full bufA/C/D/E.
    // need = FIXED + Bf*16384 + B*(16384 + 1024 + 1024 + 256)
    const int Bf = 4096;
    const size_t FULL_NEED = FIXED + (size_t)Bf * 16384ull + (size_t)B * 18688ull;

    if (ws_size >= FULL_NEED) {
        bf16_t* c1   = (bf16_t*)acts;                    // [128][Bf][64]
        bf16_t* bufA = c1 + (size_t)Bf * 8192;           // [B][8192]
        bf16_t* bufC = bufA + (size_t)B * 8192;          // [B][512]
        bf16_t* bufD = bufC + (size_t)B * 512;           // [B][512]
        bf16_t* bufE = bufD + (size_t)B * 512;           // [B][128]

        for (int c0 = 0; c0 < B; c0 += Bf) {
            conv1_kernel<<<Bf, 256, 0, stream>>>(
                xf + (size_t)c0 * 128, prm, c1, Bf);
            fused_mfma_kernel<<<dim3(Bf / 256, 128), 256, 0, stream>>>(
                c1, w2p, w3p, w4p, prm, bufA + (size_t)c0 * 8192, Bf);
        }
        gemm_mfma<<<dim3(B / 128, 4), 256, 0, stream>>>(
            bufA, w5p, prm, OFF_SC5, OFF_H5, bufC, 8192, 512);
        gemm_mfma<<<dim3(B / 128, 4), 256, 0, stream>>>(
            bufC, w6b, prm, OFF_SC6, OFF_H6, bufD, 512, 512);
        gemm_mfma<<<dim3(B / 128, 1), 256, 0, stream>>>(
            bufD, w7b, prm, OFF_SC7, OFF_H7, bufE, 512, 128);
        fc8_kernel<<<B / 32, 256, 0, stream>>>(bufE, prm, d_out, 0);
    } else {
        // fallback: everything chunked (round-4 structure)
        size_t avail = (ws_size > FIXED) ? (ws_size - FIXED) : 0;
        int Bc = 8192;
        while (Bc > 256 && (size_t)Bc * 35072ull > avail) Bc >>= 1;

        bf16_t* c1   = (bf16_t*)acts;
        bf16_t* bufA = c1 + (size_t)Bc * 8192;
        bf16_t* bufC = bufA + (size_t)Bc * 8192;
        bf16_t* bufD = bufC + (size_t)Bc * 512;
        bf16_t* bufE = bufD + (size_t)Bc * 512;

        for (int c0 = 0; c0 < B; c0 += Bc) {
            conv1_kernel<<<Bc, 256, 0, stream>>>(
                xf + (size_t)c0 * 128, prm, c1, Bc);
            fused_mfma_kernel<<<dim3(Bc / 256, 128), 256, 0, stream>>>(
                c1, w2p, w3p, w4p, prm, bufA, Bc);
            gemm_mfma<<<dim3(Bc / 128, 4), 256, 0, stream>>>(
                bufA, w5p, prm, OFF_SC5, OFF_H5, bufC, 8192, 512);
            gemm_mfma<<<dim3(Bc / 128, 4), 256, 0, stream>>>(
                bufC, w6b, prm, OFF_SC6, OFF_H6, bufD, 512, 512);
            gemm_mfma<<<dim3(Bc / 128, 1), 256, 0, stream>>>(
                bufD, w7b, prm, OFF_SC7, OFF_H7, bufE, 512, 128);
            fc8_kernel<<<Bc / 32, 256, 0, stream>>>(bufE, prm, d_out, c0);
        }
    }
}